// Round 4
// baseline (1081.329 us; speedup 1.0000x reference)
//
#include <hip/hip_runtime.h>
#include <hip/hip_bf16.h>

#define B_ 64
#define N_ 4096
#define D_ 256
#define S_ 8
#define HID_ 512

typedef __attribute__((ext_vector_type(8))) short short8;
typedef __attribute__((ext_vector_type(4))) float f32x4;

__device__ inline unsigned int f2bf(float f){
  unsigned int x = __builtin_bit_cast(unsigned int, f);
  unsigned int r = x + 0x7fffu + ((x >> 16) & 1u);
  return (r >> 16);
}
__device__ inline float bf2f(unsigned int u){
  unsigned int x = (u & 0xffffu) << 16;
  return __builtin_bit_cast(float, x);
}

// ---------------- kernel W: convert wk|wv to bf16, concat rows [512][256] ----
__global__ void kW(const float* __restrict__ wk, const float* __restrict__ wv,
                   unsigned short* __restrict__ wkv){
  int i = blockIdx.x * 256 + threadIdx.x;
  float v = (i < 256 * 256) ? wk[i] : wv[i - 256 * 256];
  wkv[i] = (unsigned short)f2bf(v);
}

// ---------------- kernel P: fused LN(inputs) + [k|v] projection -------------
// 512 thr (8 waves), wave owns 64 n-cols, B-slice resident in regs (256-VGPR
// budget via launch_bounds(512,2) -> 1 block/CU). 8 tiles of 32 rows, single
// barrier per tile with double-buffered As + two register tile buffers.
__global__ __launch_bounds__(512, 2) void kP(const float* __restrict__ xin,
    const float* __restrict__ lng, const float* __restrict__ lnb,
    const unsigned short* __restrict__ wkv,
    const float* __restrict__ bk, const float* __restrict__ bv,
    unsigned short* __restrict__ kv)
{
  __shared__ __align__(16) unsigned short As[2][32 * 32 * 8];  // 2 x 16 KiB
  const int t = threadIdx.x;
  const int w = t >> 6, lane = t & 63;
  const int lr = lane & 15, lg = lane >> 4;
  const int n0 = w * 64;
  const int row = t >> 4;        // staging row 0..31
  const int seg = t & 15;        // 16 cols each
  const long blockRow0 = (long)blockIdx.x * 256;

  // B fragments (weights), resident: [ks][nt] = 32 short8 = 128 VGPR
  short8 bfr[8][4];
#pragma unroll
  for (int ks = 0; ks < 8; ++ks)
#pragma unroll
    for (int nt = 0; nt < 4; ++nt)
      bfr[ks][nt] = *(const short8*)(wkv + (n0 + nt*16 + lr)*256 + ks*32 + lg*8);

  float4 biasr[4];
#pragma unroll
  for (int nt = 0; nt < 4; ++nt){
    int nb = n0 + nt*16 + lg*4;
    biasr[nt] = (nb < 256) ? *(const float4*)(bk + nb) : *(const float4*)(bv + nb - 256);
  }

  float4 preA[4], preB[4];

  auto LOAD = [&](float4 (&pre)[4], int tt){
    const float4* src = (const float4*)(xin + (blockRow0 + tt*32 + row) * D_) + seg * 4;
#pragma unroll
    for (int c = 0; c < 4; ++c) pre[c] = src[c];
  };

  auto LNSTORE = [&](float4 (&pre)[4], unsigned short* dst){
    float s = 0.f, ss = 0.f;
#pragma unroll
    for (int c = 0; c < 4; ++c){
      float4 f = pre[c];
      s  += f.x + f.y + f.z + f.w;
      ss += f.x*f.x + f.y*f.y + f.z*f.z + f.w*f.w;
    }
#pragma unroll
    for (int o = 1; o < 16; o <<= 1){ s += __shfl_xor(s, o); ss += __shfl_xor(ss, o); }
    const float mean = s * (1.f/256.f);
    const float rstd = rsqrtf(ss * (1.f/256.f) - mean * mean + 1e-5f);
#pragma unroll
    for (int u = 0; u < 2; ++u){
      float4 g0 = *(const float4*)(lng + seg*16 + u*8);
      float4 g1 = *(const float4*)(lng + seg*16 + u*8 + 4);
      float4 b0 = *(const float4*)(lnb + seg*16 + u*8);
      float4 b1 = *(const float4*)(lnb + seg*16 + u*8 + 4);
      float4 fa = pre[u*2], fb = pre[u*2 + 1];
      unsigned q0 = f2bf((fa.x-mean)*rstd*g0.x + b0.x) | (f2bf((fa.y-mean)*rstd*g0.y + b0.y) << 16);
      unsigned q1 = f2bf((fa.z-mean)*rstd*g0.z + b0.z) | (f2bf((fa.w-mean)*rstd*g0.w + b0.w) << 16);
      unsigned q2 = f2bf((fb.x-mean)*rstd*g1.x + b1.x) | (f2bf((fb.y-mean)*rstd*g1.y + b1.y) << 16);
      unsigned q3 = f2bf((fb.z-mean)*rstd*g1.z + b1.z) | (f2bf((fb.w-mean)*rstd*g1.w + b1.w) << 16);
      const int kc = seg*2 + u;
      unsigned byte = (((unsigned)(kc*32 + row)) << 4) ^ (((unsigned)kc & 7u) << 4);
      uint4 pk; pk.x = q0; pk.y = q1; pk.z = q2; pk.w = q3;
      *(uint4*)((char*)dst + byte) = pk;
    }
  };

  auto COMPUTE = [&](const unsigned short* buf, int tt){
    f32x4 acc[4][2];
#pragma unroll
    for (int a = 0; a < 4; ++a){ acc[a][0] = (f32x4){0,0,0,0}; acc[a][1] = (f32x4){0,0,0,0}; }
#pragma unroll
    for (int ks = 0; ks < 8; ++ks){
      const int kc = ks*4 + lg;
      const unsigned xorm = ((unsigned)kc & 7u) << 4;
      short8 af0 = *(const short8*)((const char*)buf + (((unsigned)(kc*32 + lr) << 4) ^ xorm));
      short8 af1 = *(const short8*)((const char*)buf + (((unsigned)(kc*32 + 16 + lr) << 4) ^ xorm));
#pragma unroll
      for (int nt = 0; nt < 4; ++nt){
        acc[nt][0] = __builtin_amdgcn_mfma_f32_16x16x32_bf16(bfr[ks][nt], af0, acc[nt][0], 0, 0, 0);
        acc[nt][1] = __builtin_amdgcn_mfma_f32_16x16x32_bf16(bfr[ks][nt], af1, acc[nt][1], 0, 0, 0);
      }
    }
    const long m0 = blockRow0 + tt*32;
#pragma unroll
    for (int nt = 0; nt < 4; ++nt){
      const int nb = n0 + nt*16 + lg*4;
#pragma unroll
      for (int mt = 0; mt < 2; ++mt){
        const long m = m0 + mt*16 + lr;
        unsigned p0 = f2bf(acc[nt][mt][0] + biasr[nt].x) | (f2bf(acc[nt][mt][1] + biasr[nt].y) << 16);
        unsigned p1 = f2bf(acc[nt][mt][2] + biasr[nt].z) | (f2bf(acc[nt][mt][3] + biasr[nt].w) << 16);
        uint2 pk; pk.x = p0; pk.y = p1;
        *(uint2*)(kv + m * 512 + nb) = pk;
      }
    }
  };

  LOAD(preA, 0); LNSTORE(preA, As[0]);
  LOAD(preB, 1);

#pragma unroll
  for (int pp = 0; pp < 4; ++pp){
    __syncthreads();                       // As[0] (tile 2pp) visible; As[1] readers done
    if (pp < 3) LOAD(preA, 2*pp + 2);      // in flight across COMPUTE
    LNSTORE(preB, As[1]);                  // tile 2pp+1
    COMPUTE(As[0], 2*pp);
    __syncthreads();                       // As[1] visible; As[0] readers done
    if (pp < 3){
      LOAD(preB, 2*pp + 3);
      LNSTORE(preA, As[0]);                // tile 2pp+2
    }
    COMPUTE(As[1], 2*pp + 1);
  }
}

// ---------------- kernel I: slots = mu + sigma*init; q = LN(slots)@wq^T + bq -
__global__ __launch_bounds__(256) void kI(const float* __restrict__ init,
    const float* __restrict__ mu, const float* __restrict__ sig,
    const float* __restrict__ lsg, const float* __restrict__ lsb,
    const float* __restrict__ wq, const float* __restrict__ bq,
    float* __restrict__ slots, float* __restrict__ q)
{
  const int b = blockIdx.x, t = threadIdx.x;
  __shared__ float xs[S_ * D_];
  __shared__ float red[4 * S_ * 2];
  float sv[S_];
  const float muv = mu[t], sgv = sig[t];
#pragma unroll
  for (int i = 0; i < S_; ++i){
    float x = muv + sgv * init[(b*S_ + i)*D_ + t];
    sv[i] = x;
    slots[(b*S_ + i)*D_ + t] = x;
  }
  float s[S_], qq[S_];
#pragma unroll
  for (int i = 0; i < S_; ++i){ s[i] = sv[i]; qq[i] = sv[i]*sv[i]; }
#pragma unroll
  for (int o = 1; o < 64; o <<= 1){
#pragma unroll
    for (int i = 0; i < S_; ++i){ s[i] += __shfl_xor(s[i], o); qq[i] += __shfl_xor(qq[i], o); }
  }
  const int wv_ = t >> 6;
  if ((t & 63) == 0){
#pragma unroll
    for (int i = 0; i < S_; ++i){ red[(wv_*S_ + i)*2] = s[i]; red[(wv_*S_ + i)*2 + 1] = qq[i]; }
  }
  __syncthreads();
  const float g_ = lsg[t], bv_ = lsb[t];
#pragma unroll
  for (int i = 0; i < S_; ++i){
    float S0 = 0.f, Q0 = 0.f;
#pragma unroll
    for (int w2 = 0; w2 < 4; ++w2){ S0 += red[(w2*S_ + i)*2]; Q0 += red[(w2*S_ + i)*2 + 1]; }
    float mean = S0 * (1.f/256.f), var = Q0 * (1.f/256.f) - mean*mean;
    float rstd = rsqrtf(var + 1e-5f);
    xs[i*D_ + t] = (sv[i] - mean) * rstd * g_ + bv_;
  }
  __syncthreads();
  const float4* wr = (const float4*)(wq + (long)t * D_);
  float acc[S_];
#pragma unroll
  for (int i = 0; i < S_; ++i) acc[i] = 0.f;
  for (int kc = 0; kc < 64; ++kc){
    float4 wf = wr[kc];
#pragma unroll
    for (int i = 0; i < S_; ++i){
      float4 xf = *(const float4*)(xs + i*D_ + kc*4);
      acc[i] += wf.x*xf.x + wf.y*xf.y + wf.z*xf.z + wf.w*xf.w;
    }
  }
  const float bqv = bq[t];
#pragma unroll
  for (int i = 0; i < S_; ++i) q[(b*S_ + i)*D_ + t] = acc[i] + bqv;
}

// ---------------- kernel D: MFMA dots (global k) -> softmax -> PV (LDS v) ---
// grid (16, 64), 256 thr. V slabs (32 rows) double-buffered in LDS with
// prefetch; PV LDS reads are broadcast conflict-free. Atomic num/den output
// into 2 copies (ch&1) to halve contention.
__global__ __launch_bounds__(256) void kD(const unsigned short* __restrict__ kv,
    const float* __restrict__ q, float* __restrict__ numP, float* __restrict__ denP)
{
  const int b = blockIdx.y, ch = blockIdx.x, t = threadIdx.x;
  __shared__ __align__(16) unsigned short qs[16 * 264];
  __shared__ float sw[S_ * 132];
  __shared__ float denp[4][S_];
  __shared__ __align__(16) unsigned short vbuf[2][32 * 264];
  const int lane = t & 63, w = t >> 6;
  const int lr = lane & 15, lg = lane >> 4;
  const int i_ = t >> 5, oct = t & 31;

  { // build qs (rows 0..7 = q bf16, rows 8..15 = 0)
    const int rowq = t >> 4, segq = t & 15;
    uint4 z0 = {0,0,0,0}, z1 = {0,0,0,0};
    if (rowq < 8){
      const float* qr = q + ((long)b * S_ + rowq) * D_ + segq * 16;
      float4 f0 = ((const float4*)qr)[0], f1 = ((const float4*)qr)[1];
      float4 f2 = ((const float4*)qr)[2], f3 = ((const float4*)qr)[3];
      z0.x = f2bf(f0.x)|(f2bf(f0.y)<<16); z0.y = f2bf(f0.z)|(f2bf(f0.w)<<16);
      z0.z = f2bf(f1.x)|(f2bf(f1.y)<<16); z0.w = f2bf(f1.z)|(f2bf(f1.w)<<16);
      z1.x = f2bf(f2.x)|(f2bf(f2.y)<<16); z1.y = f2bf(f2.z)|(f2bf(f2.w)<<16);
      z1.z = f2bf(f3.x)|(f2bf(f3.y)<<16); z1.w = f2bf(f3.z)|(f2bf(f3.w)<<16);
    }
    *(uint4*)(qs + rowq*264 + segq*16) = z0;
    *(uint4*)(qs + rowq*264 + segq*16 + 8) = z1;
    if (t < 32) denp[t >> 3][t & 7] = 0.f;
  }
  __syncthreads();

  short8 bqf[8];
#pragma unroll
  for (int ks = 0; ks < 8; ++ks)
    bqf[ks] = *(const short8*)(qs + lr*264 + ks*32 + lg*8);

  float acc[8] = {0,0,0,0,0,0,0,0};
  float denl = 0.f;

  uint4 vre[4];
  auto LOADV = [&](long j0, int s){
    const unsigned short* src = kv + ((long)b * N_ + j0 + s*32 + (t>>3)) * 512 + 256 + (t&7)*32;
#pragma unroll
    for (int c = 0; c < 4; ++c) vre[c] = ((const uint4*)src)[c];
  };
  auto WRITEV = [&](int buf){
    unsigned short* d = vbuf[buf] + (t>>3)*264 + (t&7)*32;
#pragma unroll
    for (int c = 0; c < 4; ++c) ((uint4*)d)[c] = vre[c];
  };
  auto ACC = [&](uint4 v, float wg){
    acc[0] += wg * bf2f(v.x); acc[1] += wg * bf2f(v.x >> 16);
    acc[2] += wg * bf2f(v.y); acc[3] += wg * bf2f(v.y >> 16);
    acc[4] += wg * bf2f(v.z); acc[5] += wg * bf2f(v.z >> 16);
    acc[6] += wg * bf2f(v.w); acc[7] += wg * bf2f(v.w >> 16);
  };
  auto PV = [&](int buf, int sbase){
    const unsigned short* vb = vbuf[buf];
    const float* swr = sw + i_ * 132 + sbase;
#pragma unroll 2
    for (int jj = 0; jj < 32; jj += 4){
      float4 w4 = *(const float4*)(swr + jj);
      uint4 v0 = *(const uint4*)(vb + (jj+0)*264 + oct*8);
      uint4 v1 = *(const uint4*)(vb + (jj+1)*264 + oct*8);
      uint4 v2 = *(const uint4*)(vb + (jj+2)*264 + oct*8);
      uint4 v3 = *(const uint4*)(vb + (jj+3)*264 + oct*8);
      ACC(v0, w4.x); ACC(v1, w4.y); ACC(v2, w4.z); ACC(v3, w4.w);
    }
  };

  for (int ph = 0; ph < 2; ++ph){
    const long j0 = (long)ch * 256 + ph * 128;
    LOADV(j0, 0);                          // in flight under dots
    // ---- dots (wave w owns rows w*32 .. +32 of this 128-phase)
#pragma unroll
    for (int tau = 0; tau < 2; ++tau){
      const long jt = j0 + w*32 + tau*16;
      const unsigned short* kr = kv + ((long)b * N_ + jt + lr) * 512;
      f32x4 d = {0,0,0,0};
#pragma unroll
      for (int ks = 0; ks < 8; ++ks){
        short8 afk = *(const short8*)(kr + ks*32 + lg*8);
        d = __builtin_amdgcn_mfma_f32_16x16x32_bf16(afk, bqf[ks], d, 0, 0, 0);
      }
#pragma unroll
      for (int r = 0; r < 4; ++r){
        float x = d[r] * 0.0625f;                     // SCALE
        float m = x;
        m = fmaxf(m, __shfl_xor(m, 1));
        m = fmaxf(m, __shfl_xor(m, 2));
        m = fmaxf(m, __shfl_xor(m, 4));
        float e = __expf(x - m);
        float ssum = e;
        ssum += __shfl_xor(ssum, 1);
        ssum += __shfl_xor(ssum, 2);
        ssum += __shfl_xor(ssum, 4);
        float wv = e / ssum + 1e-8f;
        if (lr < 8){
          sw[lr*132 + w*32 + tau*16 + lg*4 + r] = wv;
          denl += wv;
        }
      }
    }
    __syncthreads();                       // sw ready; prev-ph vbuf readers done
    WRITEV(0); LOADV(j0, 1);
    __syncthreads();                       // vbuf[0] ready
    PV(0, 0);
    WRITEV(1); LOADV(j0, 2);
    __syncthreads();                       // vbuf[1] ready; vbuf[0] readers done
    PV(1, 32);
    WRITEV(0); LOADV(j0, 3);
    __syncthreads();
    PV(0, 64);
    WRITEV(1);
    __syncthreads();
    PV(1, 96);
    __syncthreads();                       // protect sw/vbuf rewrite next ph
  }

  denl += __shfl_xor(denl, 16);
  denl += __shfl_xor(denl, 32);
  if (lane < 8) denp[w][lane] = denl;
  __syncthreads();

  float* numC = numP + (ch & 1) * 131072;
  float* denC = denP + (ch & 1) * 512;
  const long obase = ((long)b * S_ + i_) * D_ + oct * 8;
#pragma unroll
  for (int u = 0; u < 8; ++u) atomicAdd(numC + obase + u, acc[u]);
  if (t < 8) atomicAdd(denC + b*S_ + t, denp[0][t] + denp[1][t] + denp[2][t] + denp[3][t]);
}

// ---------------- kernel S: updates=num/den -> GRU -> MLP -> (q or out) -----
__device__ inline void stats2(const float v[2], float* red, int t, float* mean, float* rstd){
  float s[2], q2[2];
#pragma unroll
  for (int ii = 0; ii < 2; ++ii){ s[ii] = v[ii]; q2[ii] = v[ii]*v[ii]; }
#pragma unroll
  for (int o = 1; o < 64; o <<= 1){
#pragma unroll
    for (int ii = 0; ii < 2; ++ii){ s[ii] += __shfl_xor(s[ii], o); q2[ii] += __shfl_xor(q2[ii], o); }
  }
  const int wv = t >> 6;
  if ((t & 63) == 0){
#pragma unroll
    for (int ii = 0; ii < 2; ++ii){ red[(wv*2 + ii)*2] = s[ii]; red[(wv*2 + ii)*2 + 1] = q2[ii]; }
  }
  __syncthreads();
#pragma unroll
  for (int ii = 0; ii < 2; ++ii){
    float S0 = 0.f, Q0 = 0.f;
#pragma unroll
    for (int w2 = 0; w2 < 4; ++w2){ S0 += red[(w2*2 + ii)*2]; Q0 += red[(w2*2 + ii)*2 + 1]; }
    float m = S0 * (1.f/256.f);
    float var = Q0 * (1.f/256.f) - m*m;
    mean[ii] = m; rstd[ii] = rsqrtf(var + 1e-5f);
  }
  __syncthreads();
}

__global__ __launch_bounds__(256) void kS(
    const float* __restrict__ numP, const float* __restrict__ denP,
    const float* __restrict__ slots_in,
    const float* __restrict__ w_ih, const float* __restrict__ b_ih,
    const float* __restrict__ w_hh, const float* __restrict__ b_hh,
    const float* __restrict__ w1, const float* __restrict__ b1,
    const float* __restrict__ w2, const float* __restrict__ b2,
    const float* __restrict__ fg, const float* __restrict__ fb,
    const float* __restrict__ lsg, const float* __restrict__ lsb,
    const float* __restrict__ wq, const float* __restrict__ bq,
    float* __restrict__ outp, float* __restrict__ qout, int write_q)
{
  const int blk = blockIdx.x;
  const int b = blk >> 2, i0 = (blk & 3) * 2;
  const int t = threadIdx.x;
  __shared__ float us[2 * D_], hs[2 * D_], xs2[2 * D_];
  __shared__ float h2s[2 * HID_];
  __shared__ float red[4 * 2 * 2];
  const long base = (long)(b * S_ + i0) * D_;
  float hreg[2];
#pragma unroll
  for (int ii = 0; ii < 2; ++ii){
    int si = b*S_ + i0 + ii;
    float dv = denP[si] + denP[512 + si];
    long ni = (long)si * D_ + t;
    float u = (numP[ni] + numP[131072 + ni]) / dv;
    float h = slots_in[base + ii*D_ + t];
    us[ii*D_ + t] = u; hs[ii*D_ + t] = h; hreg[ii] = h;
  }
  __syncthreads();
  float gi_[3][2] = {{0,0},{0,0},{0,0}};
  float gh_[3][2] = {{0,0},{0,0},{0,0}};
  {
    const float4* wi0 = (const float4*)(w_ih + (long)t * D_);
    const float4* wi1 = (const float4*)(w_ih + (long)(256 + t) * D_);
    const float4* wi2 = (const float4*)(w_ih + (long)(512 + t) * D_);
    const float4* wh0 = (const float4*)(w_hh + (long)t * D_);
    const float4* wh1 = (const float4*)(w_hh + (long)(256 + t) * D_);
    const float4* wh2 = (const float4*)(w_hh + (long)(512 + t) * D_);
    for (int kc = 0; kc < 64; ++kc){
      float4 a0 = wi0[kc], a1 = wi1[kc], a2 = wi2[kc];
      float4 c0 = wh0[kc], c1 = wh1[kc], c2 = wh2[kc];
#pragma unroll
      for (int ii = 0; ii < 2; ++ii){
        float4 uf = *(const float4*)(us + ii*D_ + kc*4);
        float4 hf = *(const float4*)(hs + ii*D_ + kc*4);
        gi_[0][ii] += a0.x*uf.x + a0.y*uf.y + a0.z*uf.z + a0.w*uf.w;
        gi_[1][ii] += a1.x*uf.x + a1.y*uf.y + a1.z*uf.z + a1.w*uf.w;
        gi_[2][ii] += a2.x*uf.x + a2.y*uf.y + a2.z*uf.z + a2.w*uf.w;
        gh_[0][ii] += c0.x*hf.x + c0.y*hf.y + c0.z*hf.z + c0.w*hf.w;
        gh_[1][ii] += c1.x*hf.x + c1.y*hf.y + c1.z*hf.z + c1.w*hf.w;
        gh_[2][ii] += c2.x*hf.x + c2.y*hf.y + c2.z*hf.z + c2.w*hf.w;
      }
    }
  }
  const float bir = b_ih[t], biz = b_ih[256 + t], bin_ = b_ih[512 + t];
  const float bhr = b_hh[t], bhz = b_hh[256 + t], bhn = b_hh[512 + t];
  float nh[2];
#pragma unroll
  for (int ii = 0; ii < 2; ++ii){
    float r = 1.f / (1.f + __expf(-(gi_[0][ii] + bir + gh_[0][ii] + bhr)));
    float z = 1.f / (1.f + __expf(-(gi_[1][ii] + biz + gh_[1][ii] + bhz)));
    float n = tanhf(gi_[2][ii] + bin_ + r * (gh_[2][ii] + bhn));
    nh[ii] = (1.f - z) * n + z * hreg[ii];
  }
  float mean[2], rstd[2];
  stats2(nh, red, t, mean, rstd);
  const float fgv = fg[t], fbv = fb[t];
#pragma unroll
  for (int ii = 0; ii < 2; ++ii) xs2[ii*D_ + t] = (nh[ii] - mean[ii]) * rstd[ii] * fgv + fbv;
  __syncthreads();
#pragma unroll
  for (int go = 0; go < 2; ++go){
    int gi = go * 256 + t;
    const float4* wr = (const float4*)(w1 + (long)gi * D_);
    float a[2] = {0,0};
    for (int kc = 0; kc < 64; ++kc){
      float4 wf = wr[kc];
#pragma unroll
      for (int ii = 0; ii < 2; ++ii){
        float4 xf = *(const float4*)(xs2 + ii*D_ + kc*4);
        a[ii] += wf.x*xf.x + wf.y*xf.y + wf.z*xf.z + wf.w*xf.w;
      }
    }
    float bb = b1[gi];
#pragma unroll
    for (int ii = 0; ii < 2; ++ii) h2s[ii*HID_ + gi] = fmaxf(a[ii] + bb, 0.f);
  }
  __syncthreads();
  float outv[2];
  {
    const float4* wr = (const float4*)(w2 + (long)t * HID_);
    float a[2] = {0,0};
    for (int kc = 0; kc < 128; ++kc){
      float4 wf = wr[kc];
#pragma unroll
      for (int ii = 0; ii < 2; ++ii){
        float4 xf = *(const float4*)(h2s + ii*HID_ + kc*4);
        a[ii] += wf.x*xf.x + wf.y*xf.y + wf.z*xf.z + wf.w*xf.w;
      }
    }
    float bb = b2[t];
#pragma unroll
    for (int ii = 0; ii < 2; ++ii) outv[ii] = nh[ii] + a[ii] + bb;
  }
#pragma unroll
  for (int ii = 0; ii < 2; ++ii) outp[base + ii*D_ + t] = outv[ii];
  if (write_q){
    float mean2[2], rstd2[2];
    stats2(outv, red, t, mean2, rstd2);
    const float lg2 = lsg[t], lb2 = lsb[t];
#pragma unroll
    for (int ii = 0; ii < 2; ++ii) xs2[ii*D_ + t] = (outv[ii] - mean2[ii]) * rstd2[ii] * lg2 + lb2;
    __syncthreads();
    const float4* wr = (const float4*)(wq + (long)t * D_);
    float a[2] = {0,0};
    for (int kc = 0; kc < 64; ++kc){
      float4 wf = wr[kc];
#pragma unroll
      for (int ii = 0; ii < 2; ++ii){
        float4 xf = *(const float4*)(xs2 + ii*D_ + kc*4);
        a[ii] += wf.x*xf.x + wf.y*xf.y + wf.z*xf.z + wf.w*xf.w;
      }
    }
    float bb = bq[t];
#pragma unroll
    for (int ii = 0; ii < 2; ++ii) qout[base + ii*D_ + t] = a[ii] + bb;
  }
}

// ---------------- host ------------------------------------------------------
extern "C" void kernel_launch(void* const* d_in, const int* in_sizes, int n_in,
                              void* d_out, int out_size, void* d_ws, size_t ws_size,
                              hipStream_t stream)
{
  const float* inputs     = (const float*)d_in[0];
  const float* slots_init = (const float*)d_in[1];
  const float* slots_mu   = (const float*)d_in[2];
  const float* slots_sig  = (const float*)d_in[3];
  const float* wq   = (const float*)d_in[4];
  const float* bq   = (const float*)d_in[5];
  const float* wk   = (const float*)d_in[6];
  const float* bk   = (const float*)d_in[7];
  const float* wv   = (const float*)d_in[8];
  const float* bv   = (const float*)d_in[9];
  const float* w_ih = (const float*)d_in[10];
  const float* b_ih = (const float*)d_in[11];
  const float* w_hh = (const float*)d_in[12];
  const float* b_hh = (const float*)d_in[13];
  const float* w1   = (const float*)d_in[14];
  const float* b1   = (const float*)d_in[15];
  const float* w2   = (const float*)d_in[16];
  const float* b2   = (const float*)d_in[17];
  const float* lig  = (const float*)d_in[18];
  const float* lib  = (const float*)d_in[19];
  const float* lsg  = (const float*)d_in[20];
  const float* lsb  = (const float*)d_in[21];
  const float* ffg  = (const float*)d_in[22];
  const float* ffb  = (const float*)d_in[23];
  float* out = (float*)d_out;

  // ws layout (270,016,512 B total <= proven 270,272,512):
  //   qbuf  @ 0         (524,288)
  //   numP  @ 524,288   (1,048,576 = 2 copies) -- wkv aliases its first 256 KB
  //   denP  @ 1,572,864 (4,096 = 2 copies)
  //   kv    @ 1,576,960 (268,435,456)
  // slots lives in d_out (in-place across iterations).
  char* ws = (char*)d_ws;
  float* qbuf = (float*)(ws);
  float* numP = (float*)(ws + 524288);
  unsigned short* wkv = (unsigned short*)(ws + 524288);
  float* denP = (float*)(ws + 1572864);
  unsigned short* kv = (unsigned short*)(ws + 1576960);
  float* slots = out;

  kW<<<512, 256, 0, stream>>>(wk, wv, wkv);
  kP<<<1024, 512, 0, stream>>>(inputs, lig, lib, wkv, bk, bv, kv);
  kI<<<64, 256, 0, stream>>>(slots_init, slots_mu, slots_sig, lsg, lsb, wq, bq, slots, qbuf);
  for (int it = 0; it < 3; ++it){
    hipMemsetAsync(numP, 0, 1048576 + 4096, stream);
    kD<<<dim3(16, 64), 256, 0, stream>>>(kv, qbuf, numP, denP);
    kS<<<256, 256, 0, stream>>>(numP, denP, slots, w_ih, b_ih, w_hh, b_hh,
                                w1, b1, w2, b2, ffg, ffb, lsg, lsb, wq, bq,
                                slots, qbuf, (it < 2) ? 1 : 0);
  }
}

// Round 5
// 1023.608 us; speedup vs baseline: 1.0564x; 1.0564x over previous
//
#include <hip/hip_runtime.h>
#include <hip/hip_bf16.h>

#define B_ 64
#define N_ 4096
#define D_ 256
#define S_ 8
#define HID_ 512

typedef __attribute__((ext_vector_type(8))) short short8;
typedef __attribute__((ext_vector_type(4))) float f32x4;

__device__ inline unsigned int f2bf(float f){
  unsigned int x = __builtin_bit_cast(unsigned int, f);
  unsigned int r = x + 0x7fffu + ((x >> 16) & 1u);
  return (r >> 16);
}
__device__ inline float bf2f(unsigned int u){
  unsigned int x = (u & 0xffffu) << 16;
  return __builtin_bit_cast(float, x);
}

// ---------------- kernel W: convert wk|wv to bf16, concat rows [512][256] ----
__global__ void kW(const float* __restrict__ wk, const float* __restrict__ wv,
                   unsigned short* __restrict__ wkv){
  int i = blockIdx.x * 256 + threadIdx.x;
  float v = (i < 256 * 256) ? wk[i] : wv[i - 256 * 256];
  wkv[i] = (unsigned short)f2bf(v);
}

// ---------------- kernel P: fused LN(inputs) + [k|v] projection -------------
// 512 thr (8 waves), wave owns 64 n-cols; wkv B-slice resident in registers
// (needs 256-VGPR cap: launch_bounds(512,1) -> 1 block/CU -> 2 waves/EU).
// K-loop has zero global loads, so the x-prefetch is the only vmcnt entry.
__global__ __launch_bounds__(512, 1) void kP(const float* __restrict__ xin,
    const float* __restrict__ lng, const float* __restrict__ lnb,
    const unsigned short* __restrict__ wkv,
    const float* __restrict__ bk, const float* __restrict__ bv,
    unsigned short* __restrict__ kv)
{
  __shared__ __align__(16) unsigned short As[32 * 32 * 8];  // 16 KiB
  const int t = threadIdx.x;
  const int w = t >> 6, lane = t & 63;
  const int lr = lane & 15, lg = lane >> 4;
  const int n0 = w * 64;
  const int row = t >> 4;        // staging row 0..31
  const int seg = t & 15;        // 16 cols each
  const long blockRow0 = (long)blockIdx.x * 256;

  // B fragments (weights), resident: [ks][nt] = 32 short8 = 128 VGPR
  short8 bfr[8][4];
#pragma unroll
  for (int ks = 0; ks < 8; ++ks)
#pragma unroll
    for (int nt = 0; nt < 4; ++nt)
      bfr[ks][nt] = *(const short8*)(wkv + (n0 + nt*16 + lr)*256 + ks*32 + lg*8);

  float4 biasr[4];
#pragma unroll
  for (int nt = 0; nt < 4; ++nt){
    int nb = n0 + nt*16 + lg*4;
    biasr[nt] = (nb < 256) ? *(const float4*)(bk + nb) : *(const float4*)(bv + nb - 256);
  }

  float4 pre[4];
  auto LOAD = [&](int tt){
    const float4* src = (const float4*)(xin + (blockRow0 + tt*32 + row) * D_) + seg * 4;
#pragma unroll
    for (int c = 0; c < 4; ++c) pre[c] = src[c];
  };

  auto LNSTORE = [&](){
    float s = 0.f, ss = 0.f;
#pragma unroll
    for (int c = 0; c < 4; ++c){
      float4 f = pre[c];
      s  += f.x + f.y + f.z + f.w;
      ss += f.x*f.x + f.y*f.y + f.z*f.z + f.w*f.w;
    }
#pragma unroll
    for (int o = 1; o < 16; o <<= 1){ s += __shfl_xor(s, o); ss += __shfl_xor(ss, o); }
    const float mean = s * (1.f/256.f);
    const float rstd = rsqrtf(ss * (1.f/256.f) - mean * mean + 1e-5f);
#pragma unroll
    for (int u = 0; u < 2; ++u){
      float4 g0 = *(const float4*)(lng + seg*16 + u*8);
      float4 g1 = *(const float4*)(lng + seg*16 + u*8 + 4);
      float4 b0 = *(const float4*)(lnb + seg*16 + u*8);
      float4 b1 = *(const float4*)(lnb + seg*16 + u*8 + 4);
      float4 fa = pre[u*2], fb = pre[u*2 + 1];
      unsigned q0 = f2bf((fa.x-mean)*rstd*g0.x + b0.x) | (f2bf((fa.y-mean)*rstd*g0.y + b0.y) << 16);
      unsigned q1 = f2bf((fa.z-mean)*rstd*g0.z + b0.z) | (f2bf((fa.w-mean)*rstd*g0.w + b0.w) << 16);
      unsigned q2 = f2bf((fb.x-mean)*rstd*g1.x + b1.x) | (f2bf((fb.y-mean)*rstd*g1.y + b1.y) << 16);
      unsigned q3 = f2bf((fb.z-mean)*rstd*g1.z + b1.z) | (f2bf((fb.w-mean)*rstd*g1.w + b1.w) << 16);
      const int kc = seg*2 + u;
      unsigned byte = (((unsigned)(kc*32 + row)) << 4) ^ (((unsigned)kc & 7u) << 4);
      uint4 pk; pk.x = q0; pk.y = q1; pk.z = q2; pk.w = q3;
      *(uint4*)((char*)As + byte) = pk;
    }
  };

  LOAD(0); LNSTORE(); __syncthreads();

  for (int tt = 0; tt < 8; ++tt){
    if (tt < 7) LOAD(tt + 1);          // only thing in the vmcnt queue

    f32x4 acc[4][2];
#pragma unroll
    for (int a = 0; a < 4; ++a){ acc[a][0] = (f32x4){0,0,0,0}; acc[a][1] = (f32x4){0,0,0,0}; }
#pragma unroll
    for (int ks = 0; ks < 8; ++ks){
      const int kc = ks*4 + lg;
      const unsigned xorm = ((unsigned)kc & 7u) << 4;
      short8 af0 = *(const short8*)((const char*)As + (((unsigned)(kc*32 + lr) << 4) ^ xorm));
      short8 af1 = *(const short8*)((const char*)As + (((unsigned)(kc*32 + 16 + lr) << 4) ^ xorm));
#pragma unroll
      for (int nt = 0; nt < 4; ++nt){
        acc[nt][0] = __builtin_amdgcn_mfma_f32_16x16x32_bf16(bfr[ks][nt], af0, acc[nt][0], 0, 0, 0);
        acc[nt][1] = __builtin_amdgcn_mfma_f32_16x16x32_bf16(bfr[ks][nt], af1, acc[nt][1], 0, 0, 0);
      }
    }
    const long m0 = blockRow0 + tt*32;
#pragma unroll
    for (int nt = 0; nt < 4; ++nt){
      const int nb = n0 + nt*16 + lg*4;
#pragma unroll
      for (int mt = 0; mt < 2; ++mt){
        const long m = m0 + mt*16 + lr;
        unsigned p0 = f2bf(acc[nt][mt][0] + biasr[nt].x) | (f2bf(acc[nt][mt][1] + biasr[nt].y) << 16);
        unsigned p1 = f2bf(acc[nt][mt][2] + biasr[nt].z) | (f2bf(acc[nt][mt][3] + biasr[nt].w) << 16);
        uint2 pk; pk.x = p0; pk.y = p1;
        *(uint2*)(kv + m * 512 + nb) = pk;
      }
    }
    __syncthreads();
    if (tt < 7){ LNSTORE(); __syncthreads(); }
  }
}

// ---------------- kernel I: slots = mu + sigma*init; q = LN(slots)@wq^T + bq -
__global__ __launch_bounds__(256) void kI(const float* __restrict__ init,
    const float* __restrict__ mu, const float* __restrict__ sig,
    const float* __restrict__ lsg, const float* __restrict__ lsb,
    const float* __restrict__ wq, const float* __restrict__ bq,
    float* __restrict__ slots, float* __restrict__ q)
{
  const int b = blockIdx.x, t = threadIdx.x;
  __shared__ float xs[S_ * D_];
  __shared__ float red[4 * S_ * 2];
  float sv[S_];
  const float muv = mu[t], sgv = sig[t];
#pragma unroll
  for (int i = 0; i < S_; ++i){
    float x = muv + sgv * init[(b*S_ + i)*D_ + t];
    sv[i] = x;
    slots[(b*S_ + i)*D_ + t] = x;
  }
  float s[S_], qq[S_];
#pragma unroll
  for (int i = 0; i < S_; ++i){ s[i] = sv[i]; qq[i] = sv[i]*sv[i]; }
#pragma unroll
  for (int o = 1; o < 64; o <<= 1){
#pragma unroll
    for (int i = 0; i < S_; ++i){ s[i] += __shfl_xor(s[i], o); qq[i] += __shfl_xor(qq[i], o); }
  }
  const int wv_ = t >> 6;
  if ((t & 63) == 0){
#pragma unroll
    for (int i = 0; i < S_; ++i){ red[(wv_*S_ + i)*2] = s[i]; red[(wv_*S_ + i)*2 + 1] = qq[i]; }
  }
  __syncthreads();
  const float g_ = lsg[t], bv_ = lsb[t];
#pragma unroll
  for (int i = 0; i < S_; ++i){
    float S0 = 0.f, Q0 = 0.f;
#pragma unroll
    for (int w2 = 0; w2 < 4; ++w2){ S0 += red[(w2*S_ + i)*2]; Q0 += red[(w2*S_ + i)*2 + 1]; }
    float mean = S0 * (1.f/256.f), var = Q0 * (1.f/256.f) - mean*mean;
    float rstd = rsqrtf(var + 1e-5f);
    xs[i*D_ + t] = (sv[i] - mean) * rstd * g_ + bv_;
  }
  __syncthreads();
  const float4* wr = (const float4*)(wq + (long)t * D_);
  float acc[S_];
#pragma unroll
  for (int i = 0; i < S_; ++i) acc[i] = 0.f;
  for (int kc = 0; kc < 64; ++kc){
    float4 wf = wr[kc];
#pragma unroll
    for (int i = 0; i < S_; ++i){
      float4 xf = *(const float4*)(xs + i*D_ + kc*4);
      acc[i] += wf.x*xf.x + wf.y*xf.y + wf.z*xf.z + wf.w*xf.w;
    }
  }
  const float bqv = bq[t];
#pragma unroll
  for (int i = 0; i < S_; ++i) q[(b*S_ + i)*D_ + t] = acc[i] + bqv;
}

// ---------------- kernel D: MFMA dots (global k) -> softmax -> PV (global v)-
// grid (16, 64), 256 thr. No LDS staging of k/v (L2-resident). Atomic
// num/den into 2 copies (ch&1) to halve contention.
__global__ __launch_bounds__(256) void kD(const unsigned short* __restrict__ kv,
    const float* __restrict__ q, float* __restrict__ numP, float* __restrict__ denP)
{
  const int b = blockIdx.y, ch = blockIdx.x, t = threadIdx.x;
  __shared__ __align__(16) unsigned short qs[16 * 264];
  __shared__ float sw[S_ * 132];
  __shared__ float denp[4][S_];
  const int lane = t & 63, w = t >> 6;
  const int lr = lane & 15, lg = lane >> 4;

  { // build qs (rows 0..7 = q bf16, rows 8..15 = 0)
    const int rowq = t >> 4, segq = t & 15;
    uint4 z0 = {0,0,0,0}, z1 = {0,0,0,0};
    if (rowq < 8){
      const float* qr = q + ((long)b * S_ + rowq) * D_ + segq * 16;
      float4 f0 = ((const float4*)qr)[0], f1 = ((const float4*)qr)[1];
      float4 f2 = ((const float4*)qr)[2], f3 = ((const float4*)qr)[3];
      z0.x = f2bf(f0.x)|(f2bf(f0.y)<<16); z0.y = f2bf(f0.z)|(f2bf(f0.w)<<16);
      z0.z = f2bf(f1.x)|(f2bf(f1.y)<<16); z0.w = f2bf(f1.z)|(f2bf(f1.w)<<16);
      z1.x = f2bf(f2.x)|(f2bf(f2.y)<<16); z1.y = f2bf(f2.z)|(f2bf(f2.w)<<16);
      z1.z = f2bf(f3.x)|(f2bf(f3.y)<<16); z1.w = f2bf(f3.z)|(f2bf(f3.w)<<16);
    }
    *(uint4*)(qs + rowq*264 + segq*16) = z0;
    *(uint4*)(qs + rowq*264 + segq*16 + 8) = z1;
    if (t < 32) denp[t >> 3][t & 7] = 0.f;
  }
  __syncthreads();

  short8 bqf[8];
#pragma unroll
  for (int ks = 0; ks < 8; ++ks)
    bqf[ks] = *(const short8*)(qs + lr*264 + ks*32 + lg*8);

  float acc[8] = {0,0,0,0,0,0,0,0};
  float denl = 0.f;
  const int i_ = t >> 5, oct = t & 31;

  auto ACC = [&](uint4 v, float wg){
    acc[0] += wg * bf2f(v.x); acc[1] += wg * bf2f(v.x >> 16);
    acc[2] += wg * bf2f(v.y); acc[3] += wg * bf2f(v.y >> 16);
    acc[4] += wg * bf2f(v.z); acc[5] += wg * bf2f(v.z >> 16);
    acc[6] += wg * bf2f(v.w); acc[7] += wg * bf2f(v.w >> 16);
  };

  for (int ph = 0; ph < 2; ++ph){
    const long j0 = (long)ch * 256 + ph * 128;
    // ---- dots (wave w owns rows w*32 .. +32 of this 128-phase)
#pragma unroll
    for (int tau = 0; tau < 2; ++tau){
      const long jt = j0 + w*32 + tau*16;
      const unsigned short* kr = kv + ((long)b * N_ + jt + lr) * 512;
      f32x4 d = {0,0,0,0};
#pragma unroll
      for (int ks = 0; ks < 8; ++ks){
        short8 afk = *(const short8*)(kr + ks*32 + lg*8);
        d = __builtin_amdgcn_mfma_f32_16x16x32_bf16(afk, bqf[ks], d, 0, 0, 0);
      }
#pragma unroll
      for (int r = 0; r < 4; ++r){
        float x = d[r] * 0.0625f;                     // SCALE
        float m = x;
        m = fmaxf(m, __shfl_xor(m, 1));
        m = fmaxf(m, __shfl_xor(m, 2));
        m = fmaxf(m, __shfl_xor(m, 4));
        float e = __expf(x - m);
        float ssum = e;
        ssum += __shfl_xor(ssum, 1);
        ssum += __shfl_xor(ssum, 2);
        ssum += __shfl_xor(ssum, 4);
        float wv = e / ssum + 1e-8f;
        if (lr < 8){
          sw[lr*132 + w*32 + tau*16 + lg*4 + r] = wv;
          denl += wv;
        }
      }
    }
    __syncthreads();                                   // sw ready
    // ---- PV: thread = (slot i_, d-octet oct), v straight from L2
    const unsigned short* vrow = kv + ((long)b * N_ + j0) * 512 + 256 + oct*8;
    const float* swr = sw + i_ * 132;
    for (int jj = 0; jj < 128; jj += 4){
      uint4 v0 = *(const uint4*)(vrow + (jj+0)*512);
      uint4 v1 = *(const uint4*)(vrow + (jj+1)*512);
      uint4 v2 = *(const uint4*)(vrow + (jj+2)*512);
      uint4 v3 = *(const uint4*)(vrow + (jj+3)*512);
      float4 w4 = *(const float4*)(swr + jj);
      ACC(v0, w4.x); ACC(v1, w4.y); ACC(v2, w4.z); ACC(v3, w4.w);
    }
    __syncthreads();                                   // before sw rewrite
  }

  denl += __shfl_xor(denl, 16);
  denl += __shfl_xor(denl, 32);
  if (lane < 8) denp[w][lane] = denl;
  __syncthreads();

  float* numC = numP + (ch & 1) * 131072;
  float* denC = denP + (ch & 1) * 512;
  const long obase = ((long)b * S_ + i_) * D_ + oct * 8;
#pragma unroll
  for (int u = 0; u < 8; ++u) atomicAdd(numC + obase + u, acc[u]);
  if (t < 8) atomicAdd(denC + b*S_ + t, denp[0][t] + denp[1][t] + denp[2][t] + denp[3][t]);
}

// ---------------- kernel S: updates -> GRU -> MLP -> (q or out) -------------
// 128 blocks (4 slots each), 256 thr. GEMMs done by 8-lane groups: lane j
// reads 128B-contiguous weight-row chunks (coalesced), 4 slots share each row
// read; cross-lane shfl reduce. All weight traffic L2-coalesced.
__device__ inline void stats4(const float v[4], float* red, int t, float* mean, float* rstd){
  float s[4], q2[4];
#pragma unroll
  for (int ii = 0; ii < 4; ++ii){ s[ii] = v[ii]; q2[ii] = v[ii]*v[ii]; }
#pragma unroll
  for (int o = 1; o < 64; o <<= 1){
#pragma unroll
    for (int ii = 0; ii < 4; ++ii){ s[ii] += __shfl_xor(s[ii], o); q2[ii] += __shfl_xor(q2[ii], o); }
  }
  const int wv = t >> 6;
  if ((t & 63) == 0){
#pragma unroll
    for (int ii = 0; ii < 4; ++ii){ red[(wv*4 + ii)*2] = s[ii]; red[(wv*4 + ii)*2 + 1] = q2[ii]; }
  }
  __syncthreads();
#pragma unroll
  for (int ii = 0; ii < 4; ++ii){
    float S0 = 0.f, Q0 = 0.f;
#pragma unroll
    for (int w2 = 0; w2 < 4; ++w2){ S0 += red[(w2*4 + ii)*2]; Q0 += red[(w2*4 + ii)*2 + 1]; }
    float m = S0 * (1.f/256.f);
    float var = Q0 * (1.f/256.f) - m*m;
    mean[ii] = m; rstd[ii] = rsqrtf(var + 1e-5f);
  }
  __syncthreads();
}

__global__ __launch_bounds__(256) void kS(
    const float* __restrict__ numP, const float* __restrict__ denP,
    const float* __restrict__ slots_in,
    const float* __restrict__ w_ih, const float* __restrict__ b_ih,
    const float* __restrict__ w_hh, const float* __restrict__ b_hh,
    const float* __restrict__ w1, const float* __restrict__ b1,
    const float* __restrict__ w2, const float* __restrict__ b2,
    const float* __restrict__ fg, const float* __restrict__ fb,
    const float* __restrict__ lsg, const float* __restrict__ lsb,
    const float* __restrict__ wq, const float* __restrict__ bq,
    float* __restrict__ outp, float* __restrict__ qout, int write_q)
{
  const int blk = blockIdx.x;            // 0..127
  const int b = blk >> 1, i0 = (blk & 1) * 4;
  const int t = threadIdx.x;
  const int grp = t >> 3, j = t & 7;
  __shared__ float us[4][D_], hs[4][D_], xs2[4][D_];
  __shared__ float gi_l[4][768], gh_l[4][768];
  __shared__ float h2s[4][HID_];
  __shared__ float o2[4][D_];
  __shared__ float red[4 * 4 * 2];
  const long base = (long)(b * S_ + i0) * D_;
#pragma unroll
  for (int ii = 0; ii < 4; ++ii){
    int si = b*S_ + i0 + ii;
    float dv = denP[si] + denP[512 + si];
    long ni = (long)si * D_ + t;
    us[ii][t] = (numP[ni] + numP[131072 + ni]) / dv;
    hs[ii][t] = slots_in[base + ii*D_ + t];
  }
  __syncthreads();
  // ---- GRU gate GEMMs (N=768 each, K=256)
  for (int q = 0; q < 24; ++q){
    const int gcol = grp + q * 32;
    const float4* wi = (const float4*)(w_ih + (long)gcol * D_) + j;
    const float4* wh = (const float4*)(w_hh + (long)gcol * D_) + j;
    float ai[4] = {0,0,0,0}, ah[4] = {0,0,0,0};
#pragma unroll
    for (int c = 0; c < 8; ++c){
      float4 wf = wi[c*8];
      float4 hf = wh[c*8];
      const int k4 = (j + c*8) * 4;
#pragma unroll
      for (int ii = 0; ii < 4; ++ii){
        float4 uf = *(const float4*)(&us[ii][k4]);
        float4 hv = *(const float4*)(&hs[ii][k4]);
        ai[ii] += wf.x*uf.x + wf.y*uf.y + wf.z*uf.z + wf.w*uf.w;
        ah[ii] += hf.x*hv.x + hf.y*hv.y + hf.z*hv.z + hf.w*hv.w;
      }
    }
#pragma unroll
    for (int o = 1; o < 8; o <<= 1){
#pragma unroll
      for (int ii = 0; ii < 4; ++ii){ ai[ii] += __shfl_xor(ai[ii], o); ah[ii] += __shfl_xor(ah[ii], o); }
    }
    if (j == 0){
#pragma unroll
      for (int ii = 0; ii < 4; ++ii){ gi_l[ii][gcol] = ai[ii]; gh_l[ii][gcol] = ah[ii]; }
    }
  }
  __syncthreads();
  // ---- GRU elementwise (thread t = col t)
  const float bir = b_ih[t], biz = b_ih[256 + t], bin_ = b_ih[512 + t];
  const float bhr = b_hh[t], bhz = b_hh[256 + t], bhn = b_hh[512 + t];
  float nh[4];
#pragma unroll
  for (int ii = 0; ii < 4; ++ii){
    float r = 1.f / (1.f + __expf(-(gi_l[ii][t] + bir + gh_l[ii][t] + bhr)));
    float z = 1.f / (1.f + __expf(-(gi_l[ii][256 + t] + biz + gh_l[ii][256 + t] + bhz)));
    float n = tanhf(gi_l[ii][512 + t] + bin_ + r * (gh_l[ii][512 + t] + bhn));
    nh[ii] = (1.f - z) * n + z * hs[ii][t];
  }
  float mean[4], rstd[4];
  stats4(nh, red, t, mean, rstd);
  const float fgv = fg[t], fbv = fb[t];
#pragma unroll
  for (int ii = 0; ii < 4; ++ii) xs2[ii][t] = (nh[ii] - mean[ii]) * rstd[ii] * fgv + fbv;
  __syncthreads();
  // ---- MLP1 (N=512, K=256) + relu
  for (int q = 0; q < 16; ++q){
    const int gcol = grp + q * 32;
    const float4* wr = (const float4*)(w1 + (long)gcol * D_) + j;
    float a[4] = {0,0,0,0};
#pragma unroll
    for (int c = 0; c < 8; ++c){
      float4 wf = wr[c*8];
      const int k4 = (j + c*8) * 4;
#pragma unroll
      for (int ii = 0; ii < 4; ++ii){
        float4 xf = *(const float4*)(&xs2[ii][k4]);
        a[ii] += wf.x*xf.x + wf.y*xf.y + wf.z*xf.z + wf.w*xf.w;
      }
    }
#pragma unroll
    for (int o = 1; o < 8; o <<= 1)
#pragma unroll
      for (int ii = 0; ii < 4; ++ii) a[ii] += __shfl_xor(a[ii], o);
    if (j == 0){
      float bb = b1[gcol];
#pragma unroll
      for (int ii = 0; ii < 4; ++ii) h2s[ii][gcol] = fmaxf(a[ii] + bb, 0.f);
    }
  }
  __syncthreads();
  // ---- MLP2 (N=256, K=512)
  for (int q = 0; q < 8; ++q){
    const int gcol = grp + q * 32;
    const float4* wr = (const float4*)(w2 + (long)gcol * HID_) + j;
    float a[4] = {0,0,0,0};
#pragma unroll
    for (int c = 0; c < 16; ++c){
      float4 wf = wr[c*8];
      const int k4 = (j + c*8) * 4;
#pragma unroll
      for (int ii = 0; ii < 4; ++ii){
        float4 xf = *(const float4*)(&h2s[ii][k4]);
        a[ii] += wf.x*xf.x + wf.y*xf.y + wf.z*xf.z + wf.w*xf.w;
      }
    }
#pragma unroll
    for (int o = 1; o < 8; o <<= 1)
#pragma unroll
      for (int ii = 0; ii < 4; ++ii) a[ii] += __shfl_xor(a[ii], o);
    if (j == 0){
#pragma unroll
      for (int ii = 0; ii < 4; ++ii) o2[ii][gcol] = a[ii];
    }
  }
  __syncthreads();
  float outv[4];
  const float b2v = b2[t];
#pragma unroll
  for (int ii = 0; ii < 4; ++ii){
    outv[ii] = nh[ii] + o2[ii][t] + b2v;
    outp[base + ii*D_ + t] = outv[ii];
  }
  if (write_q){
    float mean2[4], rstd2[4];
    stats4(outv, red, t, mean2, rstd2);
    const float lg2 = lsg[t], lb2 = lsb[t];
#pragma unroll
    for (int ii = 0; ii < 4; ++ii) xs2[ii][t] = (outv[ii] - mean2[ii]) * rstd2[ii] * lg2 + lb2;
    __syncthreads();
    // ---- q = LN(out)@wq^T + bq (N=256, K=256)
    for (int q = 0; q < 8; ++q){
      const int gcol = grp + q * 32;
      const float4* wr = (const float4*)(wq + (long)gcol * D_) + j;
      float a[4] = {0,0,0,0};
#pragma unroll
      for (int c = 0; c < 8; ++c){
        float4 wf = wr[c*8];
        const int k4 = (j + c*8) * 4;
#pragma unroll
        for (int ii = 0; ii < 4; ++ii){
          float4 xf = *(const float4*)(&xs2[ii][k4]);
          a[ii] += wf.x*xf.x + wf.y*xf.y + wf.z*xf.z + wf.w*xf.w;
        }
      }
#pragma unroll
      for (int o = 1; o < 8; o <<= 1)
#pragma unroll
        for (int ii = 0; ii < 4; ++ii) a[ii] += __shfl_xor(a[ii], o);
      if (j == 0){
        float bb = bq[gcol];
#pragma unroll
        for (int ii = 0; ii < 4; ++ii) qout[(long)(b*S_ + i0 + ii)*D_ + gcol] = a[ii] + bb;
      }
    }
  }
}

// ---------------- host ------------------------------------------------------
extern "C" void kernel_launch(void* const* d_in, const int* in_sizes, int n_in,
                              void* d_out, int out_size, void* d_ws, size_t ws_size,
                              hipStream_t stream)
{
  const float* inputs     = (const float*)d_in[0];
  const float* slots_init = (const float*)d_in[1];
  const float* slots_mu   = (const float*)d_in[2];
  const float* slots_sig  = (const float*)d_in[3];
  const float* wq   = (const float*)d_in[4];
  const float* bq   = (const float*)d_in[5];
  const float* wk   = (const float*)d_in[6];
  const float* bk   = (const float*)d_in[7];
  const float* wv   = (const float*)d_in[8];
  const float* bv   = (const float*)d_in[9];
  const float* w_ih = (const float*)d_in[10];
  const float* b_ih = (const float*)d_in[11];
  const float* w_hh = (const float*)d_in[12];
  const float* b_hh = (const float*)d_in[13];
  const float* w1   = (const float*)d_in[14];
  const float* b1   = (const float*)d_in[15];
  const float* w2   = (const float*)d_in[16];
  const float* b2   = (const float*)d_in[17];
  const float* lig  = (const float*)d_in[18];
  const float* lib  = (const float*)d_in[19];
  const float* lsg  = (const float*)d_in[20];
  const float* lsb  = (const float*)d_in[21];
  const float* ffg  = (const float*)d_in[22];
  const float* ffb  = (const float*)d_in[23];
  float* out = (float*)d_out;

  // ws layout (270,016,512 B <= proven 270,272,512):
  //   qbuf  @ 0         (524,288)
  //   numP  @ 524,288   (1,048,576 = 2 copies) -- wkv aliases its first 256 KB
  //   denP  @ 1,572,864 (4,096 = 2 copies)
  //   kv    @ 1,576,960 (268,435,456)
  // slots lives in d_out (in-place across iterations).
  char* ws = (char*)d_ws;
  float* qbuf = (float*)(ws);
  float* numP = (float*)(ws + 524288);
  unsigned short* wkv = (unsigned short*)(ws + 524288);
  float* denP = (float*)(ws + 1572864);
  unsigned short* kv = (unsigned short*)(ws + 1576960);
  float* slots = out;

  kW<<<512, 256, 0, stream>>>(wk, wv, wkv);
  kP<<<1024, 512, 0, stream>>>(inputs, lig, lib, wkv, bk, bv, kv);
  kI<<<64, 256, 0, stream>>>(slots_init, slots_mu, slots_sig, lsg, lsb, wq, bq, slots, qbuf);
  for (int it = 0; it < 3; ++it){
    hipMemsetAsync(numP, 0, 1048576 + 4096, stream);
    kD<<<dim3(16, 64), 256, 0, stream>>>(kv, qbuf, numP, denP);
    kS<<<128, 256, 0, stream>>>(numP, denP, slots, w_ih, b_ih, w_hh, b_hh,
                                w1, b1, w2, b2, ffg, ffb, lsg, lsb, wq, bq,
                                slots, qbuf, (it < 2) ? 1 : 0);
  }
}

// Round 6
// 785.722 us; speedup vs baseline: 1.3762x; 1.3028x over previous
//
#include <hip/hip_runtime.h>
#include <hip/hip_bf16.h>

#define B_ 64
#define N_ 4096
#define D_ 256
#define S_ 8
#define HID_ 512

typedef __attribute__((ext_vector_type(8))) short short8;
typedef __attribute__((ext_vector_type(4))) float f32x4;

__device__ inline unsigned int f2bf(float f){
  unsigned int x = __builtin_bit_cast(unsigned int, f);
  unsigned int r = x + 0x7fffu + ((x >> 16) & 1u);
  return (r >> 16);
}
__device__ inline float bf2f(unsigned int u){
  unsigned int x = (u & 0xffffu) << 16;
  return __builtin_bit_cast(float, x);
}

// ---------------- kernel W: convert wk|wv to bf16, concat rows [512][256] ----
__global__ void kW(const float* __restrict__ wk, const float* __restrict__ wv,
                   unsigned short* __restrict__ wkv){
  int i = blockIdx.x * 256 + threadIdx.x;
  float v = (i < 256 * 256) ? wk[i] : wv[i - 256 * 256];
  wkv[i] = (unsigned short)f2bf(v);
}

// ---------------- kernel P: fused LN(inputs) + [k|v] projection -------------
// 512 thr (8 waves). Wave owns a 32-col n-slice -> bfr = 16 short8 = 64 VGPR,
// fits inside the compiler's 128-VGPR choice => truly register-resident, the
// K-loop has zero global loads. Grid 2048 = (1024 row-groups) x (2 n-halves);
// chunked XCD swizzle keeps each pair on one XCD so the second x-read hits L2.
__global__ __launch_bounds__(512) void kP(const float* __restrict__ xin,
    const float* __restrict__ lng, const float* __restrict__ lnb,
    const unsigned short* __restrict__ wkv,
    const float* __restrict__ bk, const float* __restrict__ bv,
    unsigned short* __restrict__ kv)
{
  __shared__ __align__(16) unsigned short As[32 * 32 * 8];  // 16 KiB
  const int p = blockIdx.x;
  const int lb = (p & 7) * 256 + (p >> 3);   // chunked XCD swizzle (2048 = 8*256)
  const int t = threadIdx.x;
  const int w = t >> 6, lane = t & 63;
  const int lr = lane & 15, lg = lane >> 4;
  const int n0 = (lb & 1) * 256 + w * 32;
  const int row = t >> 4;        // staging row 0..31
  const int seg = t & 15;        // 16 cols each
  const long blockRow0 = (long)(lb >> 1) * 256;

  // B fragments (weights), resident: [ks][nt] = 16 short8 = 64 VGPR
  short8 bfr[8][2];
#pragma unroll
  for (int ks = 0; ks < 8; ++ks)
#pragma unroll
    for (int nt = 0; nt < 2; ++nt)
      bfr[ks][nt] = *(const short8*)(wkv + (n0 + nt*16 + lr)*256 + ks*32 + lg*8);

  float4 biasr[2];
#pragma unroll
  for (int nt = 0; nt < 2; ++nt){
    int nb = n0 + nt*16 + lg*4;
    biasr[nt] = (nb < 256) ? *(const float4*)(bk + nb) : *(const float4*)(bv + nb - 256);
  }

  float4 pre[4];
  auto LOAD = [&](int tt){
    const float4* src = (const float4*)(xin + (blockRow0 + tt*32 + row) * D_) + seg * 4;
#pragma unroll
    for (int c = 0; c < 4; ++c) pre[c] = src[c];
  };

  auto LNSTORE = [&](){
    float s = 0.f, ss = 0.f;
#pragma unroll
    for (int c = 0; c < 4; ++c){
      float4 f = pre[c];
      s  += f.x + f.y + f.z + f.w;
      ss += f.x*f.x + f.y*f.y + f.z*f.z + f.w*f.w;
    }
#pragma unroll
    for (int o = 1; o < 16; o <<= 1){ s += __shfl_xor(s, o); ss += __shfl_xor(ss, o); }
    const float mean = s * (1.f/256.f);
    const float rstd = rsqrtf(ss * (1.f/256.f) - mean * mean + 1e-5f);
#pragma unroll
    for (int u = 0; u < 2; ++u){
      float4 g0 = *(const float4*)(lng + seg*16 + u*8);
      float4 g1 = *(const float4*)(lng + seg*16 + u*8 + 4);
      float4 b0 = *(const float4*)(lnb + seg*16 + u*8);
      float4 b1 = *(const float4*)(lnb + seg*16 + u*8 + 4);
      float4 fa = pre[u*2], fb = pre[u*2 + 1];
      unsigned q0 = f2bf((fa.x-mean)*rstd*g0.x + b0.x) | (f2bf((fa.y-mean)*rstd*g0.y + b0.y) << 16);
      unsigned q1 = f2bf((fa.z-mean)*rstd*g0.z + b0.z) | (f2bf((fa.w-mean)*rstd*g0.w + b0.w) << 16);
      unsigned q2 = f2bf((fb.x-mean)*rstd*g1.x + b1.x) | (f2bf((fb.y-mean)*rstd*g1.y + b1.y) << 16);
      unsigned q3 = f2bf((fb.z-mean)*rstd*g1.z + b1.z) | (f2bf((fb.w-mean)*rstd*g1.w + b1.w) << 16);
      const int kc = seg*2 + u;
      unsigned byte = (((unsigned)(kc*32 + row)) << 4) ^ (((unsigned)kc & 7u) << 4);
      uint4 pk; pk.x = q0; pk.y = q1; pk.z = q2; pk.w = q3;
      *(uint4*)((char*)As + byte) = pk;
    }
  };

  LOAD(0); LNSTORE(); __syncthreads();

  for (int tt = 0; tt < 8; ++tt){
    if (tt < 7) LOAD(tt + 1);          // only thing in the vmcnt queue

    f32x4 acc[2][2];
#pragma unroll
    for (int a = 0; a < 2; ++a){ acc[a][0] = (f32x4){0,0,0,0}; acc[a][1] = (f32x4){0,0,0,0}; }
#pragma unroll
    for (int ks = 0; ks < 8; ++ks){
      const int kc = ks*4 + lg;
      const unsigned xorm = ((unsigned)kc & 7u) << 4;
      short8 af0 = *(const short8*)((const char*)As + (((unsigned)(kc*32 + lr) << 4) ^ xorm));
      short8 af1 = *(const short8*)((const char*)As + (((unsigned)(kc*32 + 16 + lr) << 4) ^ xorm));
#pragma unroll
      for (int nt = 0; nt < 2; ++nt){
        acc[nt][0] = __builtin_amdgcn_mfma_f32_16x16x32_bf16(bfr[ks][nt], af0, acc[nt][0], 0, 0, 0);
        acc[nt][1] = __builtin_amdgcn_mfma_f32_16x16x32_bf16(bfr[ks][nt], af1, acc[nt][1], 0, 0, 0);
      }
    }
    const long m0 = blockRow0 + tt*32;
#pragma unroll
    for (int nt = 0; nt < 2; ++nt){
      const int nb = n0 + nt*16 + lg*4;
#pragma unroll
      for (int mt = 0; mt < 2; ++mt){
        const long m = m0 + mt*16 + lr;
        unsigned p0 = f2bf(acc[nt][mt][0] + biasr[nt].x) | (f2bf(acc[nt][mt][1] + biasr[nt].y) << 16);
        unsigned p1 = f2bf(acc[nt][mt][2] + biasr[nt].z) | (f2bf(acc[nt][mt][3] + biasr[nt].w) << 16);
        uint2 pk; pk.x = p0; pk.y = p1;
        *(uint2*)(kv + m * 512 + nb) = pk;
      }
    }
    __syncthreads();
    if (tt < 7){ LNSTORE(); __syncthreads(); }
  }
}

// ---------------- kernel I: slots = mu + sigma*init; q = LN(slots)@wq^T + bq -
__global__ __launch_bounds__(256) void kI(const float* __restrict__ init,
    const float* __restrict__ mu, const float* __restrict__ sig,
    const float* __restrict__ lsg, const float* __restrict__ lsb,
    const float* __restrict__ wq, const float* __restrict__ bq,
    float* __restrict__ slots, float* __restrict__ q)
{
  const int b = blockIdx.x, t = threadIdx.x;
  __shared__ float xs[S_ * D_];
  __shared__ float red[4 * S_ * 2];
  float sv[S_];
  const float muv = mu[t], sgv = sig[t];
#pragma unroll
  for (int i = 0; i < S_; ++i){
    float x = muv + sgv * init[(b*S_ + i)*D_ + t];
    sv[i] = x;
    slots[(b*S_ + i)*D_ + t] = x;
  }
  float s[S_], qq[S_];
#pragma unroll
  for (int i = 0; i < S_; ++i){ s[i] = sv[i]; qq[i] = sv[i]*sv[i]; }
#pragma unroll
  for (int o = 1; o < 64; o <<= 1){
#pragma unroll
    for (int i = 0; i < S_; ++i){ s[i] += __shfl_xor(s[i], o); qq[i] += __shfl_xor(qq[i], o); }
  }
  const int wv_ = t >> 6;
  if ((t & 63) == 0){
#pragma unroll
    for (int i = 0; i < S_; ++i){ red[(wv_*S_ + i)*2] = s[i]; red[(wv_*S_ + i)*2 + 1] = qq[i]; }
  }
  __syncthreads();
  const float g_ = lsg[t], bv_ = lsb[t];
#pragma unroll
  for (int i = 0; i < S_; ++i){
    float S0 = 0.f, Q0 = 0.f;
#pragma unroll
    for (int w2 = 0; w2 < 4; ++w2){ S0 += red[(w2*S_ + i)*2]; Q0 += red[(w2*S_ + i)*2 + 1]; }
    float mean = S0 * (1.f/256.f), var = Q0 * (1.f/256.f) - mean*mean;
    float rstd = rsqrtf(var + 1e-5f);
    xs[i*D_ + t] = (sv[i] - mean) * rstd * g_ + bv_;
  }
  __syncthreads();
  const float4* wr = (const float4*)(wq + (long)t * D_);
  float acc[S_];
#pragma unroll
  for (int i = 0; i < S_; ++i) acc[i] = 0.f;
  for (int kc = 0; kc < 64; ++kc){
    float4 wf = wr[kc];
#pragma unroll
    for (int i = 0; i < S_; ++i){
      float4 xf = *(const float4*)(xs + i*D_ + kc*4);
      acc[i] += wf.x*xf.x + wf.y*xf.y + wf.z*xf.z + wf.w*xf.w;
    }
  }
  const float bqv = bq[t];
#pragma unroll
  for (int i = 0; i < S_; ++i) q[(b*S_ + i)*D_ + t] = acc[i] + bqv;
}

// ---------------- kernel D: MFMA dots (global k) -> softmax -> pipelined PV -
// grid (16, 64), 256 thr. PV double-buffers 4-row register sets so the next
// L2 loads are in flight under the current ACC (T14). Atomic num/den into 2
// copies (ch&1).
__global__ __launch_bounds__(256) void kD(const unsigned short* __restrict__ kv,
    const float* __restrict__ q, float* __restrict__ numP, float* __restrict__ denP)
{
  const int b = blockIdx.y, ch = blockIdx.x, t = threadIdx.x;
  __shared__ __align__(16) unsigned short qs[16 * 264];
  __shared__ float sw[S_ * 132];
  __shared__ float denp[4][S_];
  const int lane = t & 63, w = t >> 6;
  const int lr = lane & 15, lg = lane >> 4;

  { // build qs (rows 0..7 = q bf16, rows 8..15 = 0)
    const int rowq = t >> 4, segq = t & 15;
    uint4 z0 = {0,0,0,0}, z1 = {0,0,0,0};
    if (rowq < 8){
      const float* qr = q + ((long)b * S_ + rowq) * D_ + segq * 16;
      float4 f0 = ((const float4*)qr)[0], f1 = ((const float4*)qr)[1];
      float4 f2 = ((const float4*)qr)[2], f3 = ((const float4*)qr)[3];
      z0.x = f2bf(f0.x)|(f2bf(f0.y)<<16); z0.y = f2bf(f0.z)|(f2bf(f0.w)<<16);
      z0.z = f2bf(f1.x)|(f2bf(f1.y)<<16); z0.w = f2bf(f1.z)|(f2bf(f1.w)<<16);
      z1.x = f2bf(f2.x)|(f2bf(f2.y)<<16); z1.y = f2bf(f2.z)|(f2bf(f2.w)<<16);
      z1.z = f2bf(f3.x)|(f2bf(f3.y)<<16); z1.w = f2bf(f3.z)|(f2bf(f3.w)<<16);
    }
    *(uint4*)(qs + rowq*264 + segq*16) = z0;
    *(uint4*)(qs + rowq*264 + segq*16 + 8) = z1;
    if (t < 32) denp[t >> 3][t & 7] = 0.f;
  }
  __syncthreads();

  short8 bqf[8];
#pragma unroll
  for (int ks = 0; ks < 8; ++ks)
    bqf[ks] = *(const short8*)(qs + lr*264 + ks*32 + lg*8);

  float acc[8] = {0,0,0,0,0,0,0,0};
  float denl = 0.f;
  const int i_ = t >> 5, oct = t & 31;

  auto ACC = [&](uint4 v, float wg){
    acc[0] += wg * bf2f(v.x); acc[1] += wg * bf2f(v.x >> 16);
    acc[2] += wg * bf2f(v.y); acc[3] += wg * bf2f(v.y >> 16);
    acc[4] += wg * bf2f(v.z); acc[5] += wg * bf2f(v.z >> 16);
    acc[6] += wg * bf2f(v.w); acc[7] += wg * bf2f(v.w >> 16);
  };

  for (int ph = 0; ph < 2; ++ph){
    const long j0 = (long)ch * 256 + ph * 128;
    // ---- dots (wave w owns rows w*32 .. +32 of this 128-phase)
#pragma unroll
    for (int tau = 0; tau < 2; ++tau){
      const long jt = j0 + w*32 + tau*16;
      const unsigned short* kr = kv + ((long)b * N_ + jt + lr) * 512;
      f32x4 d = {0,0,0,0};
#pragma unroll
      for (int ks = 0; ks < 8; ++ks){
        short8 afk = *(const short8*)(kr + ks*32 + lg*8);
        d = __builtin_amdgcn_mfma_f32_16x16x32_bf16(afk, bqf[ks], d, 0, 0, 0);
      }
#pragma unroll
      for (int r = 0; r < 4; ++r){
        float x = d[r] * 0.0625f;                     // SCALE
        float m = x;
        m = fmaxf(m, __shfl_xor(m, 1));
        m = fmaxf(m, __shfl_xor(m, 2));
        m = fmaxf(m, __shfl_xor(m, 4));
        float e = __expf(x - m);
        float ssum = e;
        ssum += __shfl_xor(ssum, 1);
        ssum += __shfl_xor(ssum, 2);
        ssum += __shfl_xor(ssum, 4);
        float wv = e / ssum + 1e-8f;
        if (lr < 8){
          sw[lr*132 + w*32 + tau*16 + lg*4 + r] = wv;
          denl += wv;
        }
      }
    }
    __syncthreads();                                   // sw ready
    // ---- PV: thread = (slot i_, d-octet oct), v from L2, reg double-buffer
    const unsigned short* vrow = kv + ((long)b * N_ + j0) * 512 + 256 + oct*8;
    const float* swr = sw + i_ * 132;
    uint4 va0, va1, va2, va3, vb0, vb1, vb2, vb3;
    {
      const unsigned short* p0 = vrow;
      va0 = *(const uint4*)(p0);        va1 = *(const uint4*)(p0 + 512);
      va2 = *(const uint4*)(p0 + 1024); va3 = *(const uint4*)(p0 + 1536);
    }
    for (int g = 0; g < 16; ++g){
      const unsigned short* pb = vrow + (long)(g*8 + 4) * 512;
      vb0 = *(const uint4*)(pb);        vb1 = *(const uint4*)(pb + 512);
      vb2 = *(const uint4*)(pb + 1024); vb3 = *(const uint4*)(pb + 1536);
      float4 w4 = *(const float4*)(swr + g*8);
      ACC(va0, w4.x); ACC(va1, w4.y); ACC(va2, w4.z); ACC(va3, w4.w);
      if (g < 15){
        const unsigned short* pa = vrow + (long)(g*8 + 8) * 512;
        va0 = *(const uint4*)(pa);        va1 = *(const uint4*)(pa + 512);
        va2 = *(const uint4*)(pa + 1024); va3 = *(const uint4*)(pa + 1536);
      }
      float4 w5 = *(const float4*)(swr + g*8 + 4);
      ACC(vb0, w5.x); ACC(vb1, w5.y); ACC(vb2, w5.z); ACC(vb3, w5.w);
    }
    __syncthreads();                                   // before sw rewrite
  }

  denl += __shfl_xor(denl, 16);
  denl += __shfl_xor(denl, 32);
  if (lane < 8) denp[w][lane] = denl;
  __syncthreads();

  float* numC = numP + (ch & 1) * 131072;
  float* denC = denP + (ch & 1) * 512;
  const long obase = ((long)b * S_ + i_) * D_ + oct * 8;
#pragma unroll
  for (int u = 0; u < 8; ++u) atomicAdd(numC + obase + u, acc[u]);
  if (t < 8) atomicAdd(denC + b*S_ + t, denp[0][t] + denp[1][t] + denp[2][t] + denp[3][t]);
}

// ---------------- kernel S: updates -> GRU -> MLP -> (q or out) -------------
// 256 blocks (2 slots each, 1 block/CU), 256 thr. 8-lane groups: lane j reads
// 128B-contiguous weight-row chunks (coalesced); 2 slots share each row read.
__device__ inline void stats2(const float v[2], float* red, int t, float* mean, float* rstd){
  float s[2], q2[2];
#pragma unroll
  for (int ii = 0; ii < 2; ++ii){ s[ii] = v[ii]; q2[ii] = v[ii]*v[ii]; }
#pragma unroll
  for (int o = 1; o < 64; o <<= 1){
#pragma unroll
    for (int ii = 0; ii < 2; ++ii){ s[ii] += __shfl_xor(s[ii], o); q2[ii] += __shfl_xor(q2[ii], o); }
  }
  const int wv = t >> 6;
  if ((t & 63) == 0){
#pragma unroll
    for (int ii = 0; ii < 2; ++ii){ red[(wv*2 + ii)*2] = s[ii]; red[(wv*2 + ii)*2 + 1] = q2[ii]; }
  }
  __syncthreads();
#pragma unroll
  for (int ii = 0; ii < 2; ++ii){
    float S0 = 0.f, Q0 = 0.f;
#pragma unroll
    for (int w2 = 0; w2 < 4; ++w2){ S0 += red[(w2*2 + ii)*2]; Q0 += red[(w2*2 + ii)*2 + 1]; }
    float m = S0 * (1.f/256.f);
    float var = Q0 * (1.f/256.f) - m*m;
    mean[ii] = m; rstd[ii] = rsqrtf(var + 1e-5f);
  }
  __syncthreads();
}

__global__ __launch_bounds__(256) void kS(
    const float* __restrict__ numP, const float* __restrict__ denP,
    const float* __restrict__ slots_in,
    const float* __restrict__ w_ih, const float* __restrict__ b_ih,
    const float* __restrict__ w_hh, const float* __restrict__ b_hh,
    const float* __restrict__ w1, const float* __restrict__ b1,
    const float* __restrict__ w2, const float* __restrict__ b2,
    const float* __restrict__ fg, const float* __restrict__ fb,
    const float* __restrict__ lsg, const float* __restrict__ lsb,
    const float* __restrict__ wq, const float* __restrict__ bq,
    float* __restrict__ outp, float* __restrict__ qout, int write_q)
{
  const int blk = blockIdx.x;            // 0..255
  const int b = blk >> 2, i0 = (blk & 3) * 2;
  const int t = threadIdx.x;
  const int grp = t >> 3, j = t & 7;
  __shared__ float us[2][D_], hs[2][D_], xs2[2][D_];
  __shared__ float gi_l[2][768], gh_l[2][768];
  __shared__ float h2s[2][HID_];
  __shared__ float o2[2][D_];
  __shared__ float red[4 * 2 * 2];
  const long base = (long)(b * S_ + i0) * D_;
#pragma unroll
  for (int ii = 0; ii < 2; ++ii){
    int si = b*S_ + i0 + ii;
    float dv = denP[si] + denP[512 + si];
    long ni = (long)si * D_ + t;
    us[ii][t] = (numP[ni] + numP[131072 + ni]) / dv;
    hs[ii][t] = slots_in[base + ii*D_ + t];
  }
  __syncthreads();
  // ---- GRU gate GEMMs (N=768 each, K=256), 32 rows per q-iter
  for (int q = 0; q < 24; ++q){
    const int gcol = grp + q * 32;
    const float4* wi = (const float4*)(w_ih + (long)gcol * D_) + j;
    const float4* wh = (const float4*)(w_hh + (long)gcol * D_) + j;
    float ai[2] = {0,0}, ah[2] = {0,0};
#pragma unroll
    for (int c = 0; c < 8; ++c){
      float4 wf = wi[c*8];
      float4 hf = wh[c*8];
      const int k4 = (j + c*8) * 4;
#pragma unroll
      for (int ii = 0; ii < 2; ++ii){
        float4 uf = *(const float4*)(&us[ii][k4]);
        float4 hv = *(const float4*)(&hs[ii][k4]);
        ai[ii] += wf.x*uf.x + wf.y*uf.y + wf.z*uf.z + wf.w*uf.w;
        ah[ii] += hf.x*hv.x + hf.y*hv.y + hf.z*hv.z + hf.w*hv.w;
      }
    }
#pragma unroll
    for (int o = 1; o < 8; o <<= 1){
#pragma unroll
      for (int ii = 0; ii < 2; ++ii){ ai[ii] += __shfl_xor(ai[ii], o); ah[ii] += __shfl_xor(ah[ii], o); }
    }
    if (j == 0){
#pragma unroll
      for (int ii = 0; ii < 2; ++ii){ gi_l[ii][gcol] = ai[ii]; gh_l[ii][gcol] = ah[ii]; }
    }
  }
  __syncthreads();
  // ---- GRU elementwise (thread t = col t)
  const float bir = b_ih[t], biz = b_ih[256 + t], bin_ = b_ih[512 + t];
  const float bhr = b_hh[t], bhz = b_hh[256 + t], bhn = b_hh[512 + t];
  float nh[2];
#pragma unroll
  for (int ii = 0; ii < 2; ++ii){
    float r = 1.f / (1.f + __expf(-(gi_l[ii][t] + bir + gh_l[ii][t] + bhr)));
    float z = 1.f / (1.f + __expf(-(gi_l[ii][256 + t] + biz + gh_l[ii][256 + t] + bhz)));
    float n = tanhf(gi_l[ii][512 + t] + bin_ + r * (gh_l[ii][512 + t] + bhn));
    nh[ii] = (1.f - z) * n + z * hs[ii][t];
  }
  float mean[2], rstd[2];
  stats2(nh, red, t, mean, rstd);
  const float fgv = fg[t], fbv = fb[t];
#pragma unroll
  for (int ii = 0; ii < 2; ++ii) xs2[ii][t] = (nh[ii] - mean[ii]) * rstd[ii] * fgv + fbv;
  __syncthreads();
  // ---- MLP1 (N=512, K=256) + relu
  for (int q = 0; q < 16; ++q){
    const int gcol = grp + q * 32;
    const float4* wr = (const float4*)(w1 + (long)gcol * D_) + j;
    float a[2] = {0,0};
#pragma unroll
    for (int c = 0; c < 8; ++c){
      float4 wf = wr[c*8];
      const int k4 = (j + c*8) * 4;
#pragma unroll
      for (int ii = 0; ii < 2; ++ii){
        float4 xf = *(const float4*)(&xs2[ii][k4]);
        a[ii] += wf.x*xf.x + wf.y*xf.y + wf.z*xf.z + wf.w*xf.w;
      }
    }
#pragma unroll
    for (int o = 1; o < 8; o <<= 1)
#pragma unroll
      for (int ii = 0; ii < 2; ++ii) a[ii] += __shfl_xor(a[ii], o);
    if (j == 0){
      float bb = b1[gcol];
#pragma unroll
      for (int ii = 0; ii < 2; ++ii) h2s[ii][gcol] = fmaxf(a[ii] + bb, 0.f);
    }
  }
  __syncthreads();
  // ---- MLP2 (N=256, K=512)
  for (int q = 0; q < 8; ++q){
    const int gcol = grp + q * 32;
    const float4* wr = (const float4*)(w2 + (long)gcol * HID_) + j;
    float a[2] = {0,0};
#pragma unroll
    for (int c = 0; c < 16; ++c){
      float4 wf = wr[c*8];
      const int k4 = (j + c*8) * 4;
#pragma unroll
      for (int ii = 0; ii < 2; ++ii){
        float4 xf = *(const float4*)(&h2s[ii][k4]);
        a[ii] += wf.x*xf.x + wf.y*xf.y + wf.z*xf.z + wf.w*xf.w;
      }
    }
#pragma unroll
    for (int o = 1; o < 8; o <<= 1)
#pragma unroll
      for (int ii = 0; ii < 2; ++ii) a[ii] += __shfl_xor(a[ii], o);
    if (j == 0){
#pragma unroll
      for (int ii = 0; ii < 2; ++ii) o2[ii][gcol] = a[ii];
    }
  }
  __syncthreads();
  float outv[2];
  const float b2v = b2[t];
#pragma unroll
  for (int ii = 0; ii < 2; ++ii){
    outv[ii] = nh[ii] + o2[ii][t] + b2v;
    outp[base + ii*D_ + t] = outv[ii];
  }
  if (write_q){
    float mean2[2], rstd2[2];
    stats2(outv, red, t, mean2, rstd2);
    const float lg2 = lsg[t], lb2 = lsb[t];
#pragma unroll
    for (int ii = 0; ii < 2; ++ii) xs2[ii][t] = (outv[ii] - mean2[ii]) * rstd2[ii] * lg2 + lb2;
    __syncthreads();
    // ---- q = LN(out)@wq^T + bq (N=256, K=256)
    for (int q = 0; q < 8; ++q){
      const int gcol = grp + q * 32;
      const float4* wr = (const float4*)(wq + (long)gcol * D_) + j;
      float a[2] = {0,0};
#pragma unroll
      for (int c = 0; c < 8; ++c){
        float4 wf = wr[c*8];
        const int k4 = (j + c*8) * 4;
#pragma unroll
        for (int ii = 0; ii < 2; ++ii){
          float4 xf = *(const float4*)(&xs2[ii][k4]);
          a[ii] += wf.x*xf.x + wf.y*xf.y + wf.z*xf.z + wf.w*xf.w;
        }
      }
#pragma unroll
      for (int o = 1; o < 8; o <<= 1)
#pragma unroll
        for (int ii = 0; ii < 2; ++ii) a[ii] += __shfl_xor(a[ii], o);
      if (j == 0){
        float bb = bq[gcol];
#pragma unroll
        for (int ii = 0; ii < 2; ++ii) qout[(long)(b*S_ + i0 + ii)*D_ + gcol] = a[ii] + bb;
      }
    }
  }
}

// ---------------- host ------------------------------------------------------
extern "C" void kernel_launch(void* const* d_in, const int* in_sizes, int n_in,
                              void* d_out, int out_size, void* d_ws, size_t ws_size,
                              hipStream_t stream)
{
  const float* inputs     = (const float*)d_in[0];
  const float* slots_init = (const float*)d_in[1];
  const float* slots_mu   = (const float*)d_in[2];
  const float* slots_sig  = (const float*)d_in[3];
  const float* wq   = (const float*)d_in[4];
  const float* bq   = (const float*)d_in[5];
  const float* wk   = (const float*)d_in[6];
  const float* bk   = (const float*)d_in[7];
  const float* wv   = (const float*)d_in[8];
  const float* bv   = (const float*)d_in[9];
  const float* w_ih = (const float*)d_in[10];
  const float* b_ih = (const float*)d_in[11];
  const float* w_hh = (const float*)d_in[12];
  const float* b_hh = (const float*)d_in[13];
  const float* w1   = (const float*)d_in[14];
  const float* b1   = (const float*)d_in[15];
  const float* w2   = (const float*)d_in[16];
  const float* b2   = (const float*)d_in[17];
  const float* lig  = (const float*)d_in[18];
  const float* lib  = (const float*)d_in[19];
  const float* lsg  = (const float*)d_in[20];
  const float* lsb  = (const float*)d_in[21];
  const float* ffg  = (const float*)d_in[22];
  const float* ffb  = (const float*)d_in[23];
  float* out = (float*)d_out;

  // ws layout (270,016,512 B <= proven):
  //   qbuf  @ 0         (524,288)
  //   numP  @ 524,288   (1,048,576 = 2 copies) -- wkv aliases its first 256 KB
  //   denP  @ 1,572,864 (4,096 = 2 copies)
  //   kv    @ 1,576,960 (268,435,456)
  // slots lives in d_out (in-place across iterations).
  char* ws = (char*)d_ws;
  float* qbuf = (float*)(ws);
  float* numP = (float*)(ws + 524288);
  unsigned short* wkv = (unsigned short*)(ws + 524288);
  float* denP = (float*)(ws + 1572864);
  unsigned short* kv = (unsigned short*)(ws + 1576960);
  float* slots = out;

  kW<<<512, 256, 0, stream>>>(wk, wv, wkv);
  kP<<<2048, 512, 0, stream>>>(inputs, lig, lib, wkv, bk, bv, kv);
  kI<<<64, 256, 0, stream>>>(slots_init, slots_mu, slots_sig, lsg, lsb, wq, bq, slots, qbuf);
  for (int it = 0; it < 3; ++it){
    hipMemsetAsync(numP, 0, 1048576 + 4096, stream);
    kD<<<dim3(16, 64), 256, 0, stream>>>(kv, qbuf, numP, denP);
    kS<<<256, 256, 0, stream>>>(numP, denP, slots, w_ih, b_ih, w_hh, b_hh,
                                w1, b1, w2, b2, ffg, ffb, lsg, lsb, wq, bq,
                                slots, qbuf, (it < 2) ? 1 : 0);
  }
}

// Round 7
// 780.858 us; speedup vs baseline: 1.3848x; 1.0062x over previous
//
#include <hip/hip_runtime.h>
#include <hip/hip_bf16.h>

#define B_ 64
#define N_ 4096
#define D_ 256
#define S_ 8
#define HID_ 512

typedef __attribute__((ext_vector_type(8))) short short8;
typedef __attribute__((ext_vector_type(4))) float f32x4;

__device__ inline unsigned int f2bf(float f){
  unsigned int x = __builtin_bit_cast(unsigned int, f);
  unsigned int r = x + 0x7fffu + ((x >> 16) & 1u);
  return (r >> 16);
}
__device__ inline float bf2f(unsigned int u){
  unsigned int x = (u & 0xffffu) << 16;
  return __builtin_bit_cast(float, x);
}

// ---------------- kernel W: convert wk|wv to bf16, concat rows [512][256] ----
__global__ void kW(const float* __restrict__ wk, const float* __restrict__ wv,
                   unsigned short* __restrict__ wkv){
  int i = blockIdx.x * 256 + threadIdx.x;
  float v = (i < 256 * 256) ? wk[i] : wv[i - 256 * 256];
  wkv[i] = (unsigned short)f2bf(v);
}

// ---------------- kernel LN: x_hat = LN(inputs) -> bf16, into kv k-halves ---
// Pure streaming: 268 MB read + 134 MB write. Wave = 1 row/iter; x_hat[r]
// stored at kv[r][0..255] (aliased; kG consumes then overwrites).
__global__ __launch_bounds__(256) void kLN(const float* __restrict__ xin,
    const float* __restrict__ lng, const float* __restrict__ lnb,
    unsigned short* __restrict__ kvout)
{
  const int t = threadIdx.x;
  const int wv = t >> 6, lane = t & 63;
  const float4 g4 = *(const float4*)(lng + lane * 4);
  const float4 b4 = *(const float4*)(lnb + lane * 4);
  for (int it = 0; it < 32; ++it){
    const long r = (long)it * 8192 + blockIdx.x * 4 + wv;
    float4 f = *(const float4*)(xin + r * 256 + lane * 4);
    float s  = f.x + f.y + f.z + f.w;
    float ss = f.x*f.x + f.y*f.y + f.z*f.z + f.w*f.w;
#pragma unroll
    for (int o = 1; o < 64; o <<= 1){ s += __shfl_xor(s, o); ss += __shfl_xor(ss, o); }
    const float mean = s * (1.f/256.f);
    const float rstd = rsqrtf(ss * (1.f/256.f) - mean * mean + 1e-5f);
    unsigned p0 = f2bf((f.x - mean)*rstd*g4.x + b4.x) | (f2bf((f.y - mean)*rstd*g4.y + b4.y) << 16);
    unsigned p1 = f2bf((f.z - mean)*rstd*g4.z + b4.z) | (f2bf((f.w - mean)*rstd*g4.w + b4.w) << 16);
    uint2 pk; pk.x = p0; pk.y = p1;
    *(uint2*)(kvout + r * 512 + lane * 4) = pk;
  }
}

// ---------------- kernel G: kv = x_hat @ wkv^T + bias (bf16 MFMA) -----------
// 512 thr (8 waves), one 64-row m-tile per block (grid 4096). A staged 32 KB
// in LDS (reg-staged, XOR write-swizzle -> 2-way-conflict frag reads). Two
// sequential n-half passes: bfr = 16 short8 = 64 VGPR resident per pass.
// Reads x_hat from kv[r][0..255]; k-half store overwrites it (post-barrier).
__global__ __launch_bounds__(512) void kG(
    const unsigned short* __restrict__ wkv,
    const float* __restrict__ bk, const float* __restrict__ bv,
    unsigned short* kv)
{
  __shared__ __align__(16) unsigned short As[64 * 256];   // 32 KiB
  const int t = threadIdx.x;
  const int w = t >> 6, lane = t & 63;
  const int lr = lane & 15, lg = lane >> 4;
  const long row0 = (long)blockIdx.x * 64;

  // ---- stage A: read global unit (r,u) of x_hat, write LDS unit (r, u^(r&7))
#pragma unroll
  for (int c = 0; c < 4; ++c){
    const int l = c * 512 + t;
    const int r = l >> 5, u = l & 31;
    uint4 val = *(const uint4*)(kv + (row0 + r) * 512 + u * 8);
    *(uint4*)(As + (r * 32 + (u ^ (r & 7))) * 8) = val;
  }
  __syncthreads();

  for (int nh = 0; nh < 2; ++nh){
    const int n0 = nh * 256 + w * 32;
    short8 bfr[8][2];
#pragma unroll
    for (int ks = 0; ks < 8; ++ks)
#pragma unroll
      for (int nt = 0; nt < 2; ++nt)
        bfr[ks][nt] = *(const short8*)(wkv + (n0 + nt*16 + lr)*256 + ks*32 + lg*8);
    float4 biasr[2];
#pragma unroll
    for (int nt = 0; nt < 2; ++nt){
      int nb = n0 + nt*16 + lg*4;
      biasr[nt] = (nb < 256) ? *(const float4*)(bk + nb) : *(const float4*)(bv + nb - 256);
    }

    f32x4 acc[2][4];
#pragma unroll
    for (int a = 0; a < 2; ++a)
#pragma unroll
      for (int m2 = 0; m2 < 4; ++m2) acc[a][m2] = (f32x4){0.f,0.f,0.f,0.f};

#pragma unroll
    for (int ks = 0; ks < 8; ++ks){
      short8 af[4];
#pragma unroll
      for (int mt = 0; mt < 4; ++mt){
        const int row = mt*16 + lr;
        const int u = (ks*4 + lg) ^ (lr & 7);
        af[mt] = *(const short8*)(As + row*256 + u*8);
      }
#pragma unroll
      for (int nt = 0; nt < 2; ++nt)
#pragma unroll
        for (int mt = 0; mt < 4; ++mt)
          acc[nt][mt] = __builtin_amdgcn_mfma_f32_16x16x32_bf16(bfr[ks][nt], af[mt], acc[nt][mt], 0, 0, 0);
    }

#pragma unroll
    for (int nt = 0; nt < 2; ++nt){
      const int nb = n0 + nt*16 + lg*4;
#pragma unroll
      for (int mt = 0; mt < 4; ++mt){
        const long m = row0 + mt*16 + lr;
        unsigned p0 = f2bf(acc[nt][mt][0] + biasr[nt].x) | (f2bf(acc[nt][mt][1] + biasr[nt].y) << 16);
        unsigned p1 = f2bf(acc[nt][mt][2] + biasr[nt].z) | (f2bf(acc[nt][mt][3] + biasr[nt].w) << 16);
        uint2 pk; pk.x = p0; pk.y = p1;
        *(uint2*)(kv + m * 512 + nb) = pk;
      }
    }
  }
}

// ---------------- kernel I: slots = mu + sigma*init; q = LN(slots)@wq^T + bq -
__global__ __launch_bounds__(256) void kI(const float* __restrict__ init,
    const float* __restrict__ mu, const float* __restrict__ sig,
    const float* __restrict__ lsg, const float* __restrict__ lsb,
    const float* __restrict__ wq, const float* __restrict__ bq,
    float* __restrict__ slots, float* __restrict__ q)
{
  const int b = blockIdx.x, t = threadIdx.x;
  __shared__ float xs[S_ * D_];
  __shared__ float red[4 * S_ * 2];
  float sv[S_];
  const float muv = mu[t], sgv = sig[t];
#pragma unroll
  for (int i = 0; i < S_; ++i){
    float x = muv + sgv * init[(b*S_ + i)*D_ + t];
    sv[i] = x;
    slots[(b*S_ + i)*D_ + t] = x;
  }
  float s[S_], qq[S_];
#pragma unroll
  for (int i = 0; i < S_; ++i){ s[i] = sv[i]; qq[i] = sv[i]*sv[i]; }
#pragma unroll
  for (int o = 1; o < 64; o <<= 1){
#pragma unroll
    for (int i = 0; i < S_; ++i){ s[i] += __shfl_xor(s[i], o); qq[i] += __shfl_xor(qq[i], o); }
  }
  const int wv_ = t >> 6;
  if ((t & 63) == 0){
#pragma unroll
    for (int i = 0; i < S_; ++i){ red[(wv_*S_ + i)*2] = s[i]; red[(wv_*S_ + i)*2 + 1] = qq[i]; }
  }
  __syncthreads();
  const float g_ = lsg[t], bv_ = lsb[t];
#pragma unroll
  for (int i = 0; i < S_; ++i){
    float S0 = 0.f, Q0 = 0.f;
#pragma unroll
    for (int w2 = 0; w2 < 4; ++w2){ S0 += red[(w2*S_ + i)*2]; Q0 += red[(w2*S_ + i)*2 + 1]; }
    float mean = S0 * (1.f/256.f), var = Q0 * (1.f/256.f) - mean*mean;
    float rstd = rsqrtf(var + 1e-5f);
    xs[i*D_ + t] = (sv[i] - mean) * rstd * g_ + bv_;
  }
  __syncthreads();
  const float4* wr = (const float4*)(wq + (long)t * D_);
  float acc[S_];
#pragma unroll
  for (int i = 0; i < S_; ++i) acc[i] = 0.f;
  for (int kc = 0; kc < 64; ++kc){
    float4 wf = wr[kc];
#pragma unroll
    for (int i = 0; i < S_; ++i){
      float4 xf = *(const float4*)(xs + i*D_ + kc*4);
      acc[i] += wf.x*xf.x + wf.y*xf.y + wf.z*xf.z + wf.w*xf.w;
    }
  }
  const float bqv = bq[t];
#pragma unroll
  for (int i = 0; i < S_; ++i) q[(b*S_ + i)*D_ + t] = acc[i] + bqv;
}

// ---------------- kernel D: MFMA dots (global k) -> softmax -> pipelined PV -
__global__ __launch_bounds__(256) void kD(const unsigned short* __restrict__ kv,
    const float* __restrict__ q, float* __restrict__ numP, float* __restrict__ denP)
{
  const int b = blockIdx.y, ch = blockIdx.x, t = threadIdx.x;
  __shared__ __align__(16) unsigned short qs[16 * 264];
  __shared__ float sw[S_ * 132];
  __shared__ float denp[4][S_];
  const int lane = t & 63, w = t >> 6;
  const int lr = lane & 15, lg = lane >> 4;

  { // build qs (rows 0..7 = q bf16, rows 8..15 = 0)
    const int rowq = t >> 4, segq = t & 15;
    uint4 z0 = {0,0,0,0}, z1 = {0,0,0,0};
    if (rowq < 8){
      const float* qr = q + ((long)b * S_ + rowq) * D_ + segq * 16;
      float4 f0 = ((const float4*)qr)[0], f1 = ((const float4*)qr)[1];
      float4 f2 = ((const float4*)qr)[2], f3 = ((const float4*)qr)[3];
      z0.x = f2bf(f0.x)|(f2bf(f0.y)<<16); z0.y = f2bf(f0.z)|(f2bf(f0.w)<<16);
      z0.z = f2bf(f1.x)|(f2bf(f1.y)<<16); z0.w = f2bf(f1.z)|(f2bf(f1.w)<<16);
      z1.x = f2bf(f2.x)|(f2bf(f2.y)<<16); z1.y = f2bf(f2.z)|(f2bf(f2.w)<<16);
      z1.z = f2bf(f3.x)|(f2bf(f3.y)<<16); z1.w = f2bf(f3.z)|(f2bf(f3.w)<<16);
    }
    *(uint4*)(qs + rowq*264 + segq*16) = z0;
    *(uint4*)(qs + rowq*264 + segq*16 + 8) = z1;
    if (t < 32) denp[t >> 3][t & 7] = 0.f;
  }
  __syncthreads();

  short8 bqf[8];
#pragma unroll
  for (int ks = 0; ks < 8; ++ks)
    bqf[ks] = *(const short8*)(qs + lr*264 + ks*32 + lg*8);

  float acc[8] = {0,0,0,0,0,0,0,0};
  float denl = 0.f;
  const int i_ = t >> 5, oct = t & 31;

  auto ACC = [&](uint4 v, float wg){
    acc[0] += wg * bf2f(v.x); acc[1] += wg * bf2f(v.x >> 16);
    acc[2] += wg * bf2f(v.y); acc[3] += wg * bf2f(v.y >> 16);
    acc[4] += wg * bf2f(v.z); acc[5] += wg * bf2f(v.z >> 16);
    acc[6] += wg * bf2f(v.w); acc[7] += wg * bf2f(v.w >> 16);
  };

  for (int ph = 0; ph < 2; ++ph){
    const long j0 = (long)ch * 256 + ph * 128;
#pragma unroll
    for (int tau = 0; tau < 2; ++tau){
      const long jt = j0 + w*32 + tau*16;
      const unsigned short* kr = kv + ((long)b * N_ + jt + lr) * 512;
      f32x4 d = {0,0,0,0};
#pragma unroll
      for (int ks = 0; ks < 8; ++ks){
        short8 afk = *(const short8*)(kr + ks*32 + lg*8);
        d = __builtin_amdgcn_mfma_f32_16x16x32_bf16(afk, bqf[ks], d, 0, 0, 0);
      }
#pragma unroll
      for (int r = 0; r < 4; ++r){
        float x = d[r] * 0.0625f;                     // SCALE
        float m = x;
        m = fmaxf(m, __shfl_xor(m, 1));
        m = fmaxf(m, __shfl_xor(m, 2));
        m = fmaxf(m, __shfl_xor(m, 4));
        float e = __expf(x - m);
        float ssum = e;
        ssum += __shfl_xor(ssum, 1);
        ssum += __shfl_xor(ssum, 2);
        ssum += __shfl_xor(ssum, 4);
        float wv = e / ssum + 1e-8f;
        if (lr < 8){
          sw[lr*132 + w*32 + tau*16 + lg*4 + r] = wv;
          denl += wv;
        }
      }
    }
    __syncthreads();                                   // sw ready
    const unsigned short* vrow = kv + ((long)b * N_ + j0) * 512 + 256 + oct*8;
    const float* swr = sw + i_ * 132;
    uint4 va0, va1, va2, va3, vb0, vb1, vb2, vb3;
    {
      const unsigned short* p0 = vrow;
      va0 = *(const uint4*)(p0);        va1 = *(const uint4*)(p0 + 512);
      va2 = *(const uint4*)(p0 + 1024); va3 = *(const uint4*)(p0 + 1536);
    }
    for (int g = 0; g < 16; ++g){
      const unsigned short* pb = vrow + (long)(g*8 + 4) * 512;
      vb0 = *(const uint4*)(pb);        vb1 = *(const uint4*)(pb + 512);
      vb2 = *(const uint4*)(pb + 1024); vb3 = *(const uint4*)(pb + 1536);
      float4 w4 = *(const float4*)(swr + g*8);
      ACC(va0, w4.x); ACC(va1, w4.y); ACC(va2, w4.z); ACC(va3, w4.w);
      if (g < 15){
        const unsigned short* pa = vrow + (long)(g*8 + 8) * 512;
        va0 = *(const uint4*)(pa);        va1 = *(const uint4*)(pa + 512);
        va2 = *(const uint4*)(pa + 1024); va3 = *(const uint4*)(pa + 1536);
      }
      float4 w5 = *(const float4*)(swr + g*8 + 4);
      ACC(vb0, w5.x); ACC(vb1, w5.y); ACC(vb2, w5.z); ACC(vb3, w5.w);
    }
    __syncthreads();                                   // before sw rewrite
  }

  denl += __shfl_xor(denl, 16);
  denl += __shfl_xor(denl, 32);
  if (lane < 8) denp[w][lane] = denl;
  __syncthreads();

  float* numC = numP + (ch & 1) * 131072;
  float* denC = denP + (ch & 1) * 512;
  const long obase = ((long)b * S_ + i_) * D_ + oct * 8;
#pragma unroll
  for (int u = 0; u < 8; ++u) atomicAdd(numC + obase + u, acc[u]);
  if (t < 8) atomicAdd(denC + b*S_ + t, denp[0][t] + denp[1][t] + denp[2][t] + denp[3][t]);
}

// ---------------- kernel S: updates -> GRU -> MLP -> (q or out) -------------
__device__ inline void stats2(const float v[2], float* red, int t, float* mean, float* rstd){
  float s[2], q2[2];
#pragma unroll
  for (int ii = 0; ii < 2; ++ii){ s[ii] = v[ii]; q2[ii] = v[ii]*v[ii]; }
#pragma unroll
  for (int o = 1; o < 64; o <<= 1){
#pragma unroll
    for (int ii = 0; ii < 2; ++ii){ s[ii] += __shfl_xor(s[ii], o); q2[ii] += __shfl_xor(q2[ii], o); }
  }
  const int wv = t >> 6;
  if ((t & 63) == 0){
#pragma unroll
    for (int ii = 0; ii < 2; ++ii){ red[(wv*2 + ii)*2] = s[ii]; red[(wv*2 + ii)*2 + 1] = q2[ii]; }
  }
  __syncthreads();
#pragma unroll
  for (int ii = 0; ii < 2; ++ii){
    float S0 = 0.f, Q0 = 0.f;
#pragma unroll
    for (int w2 = 0; w2 < 4; ++w2){ S0 += red[(w2*2 + ii)*2]; Q0 += red[(w2*2 + ii)*2 + 1]; }
    float m = S0 * (1.f/256.f);
    float var = Q0 * (1.f/256.f) - m*m;
    mean[ii] = m; rstd[ii] = rsqrtf(var + 1e-5f);
  }
  __syncthreads();
}

__global__ __launch_bounds__(256) void kS(
    const float* __restrict__ numP, const float* __restrict__ denP,
    const float* __restrict__ slots_in,
    const float* __restrict__ w_ih, const float* __restrict__ b_ih,
    const float* __restrict__ w_hh, const float* __restrict__ b_hh,
    const float* __restrict__ w1, const float* __restrict__ b1,
    const float* __restrict__ w2, const float* __restrict__ b2,
    const float* __restrict__ fg, const float* __restrict__ fb,
    const float* __restrict__ lsg, const float* __restrict__ lsb,
    const float* __restrict__ wq, const float* __restrict__ bq,
    float* __restrict__ outp, float* __restrict__ qout, int write_q)
{
  const int blk = blockIdx.x;            // 0..255
  const int b = blk >> 2, i0 = (blk & 3) * 2;
  const int t = threadIdx.x;
  const int grp = t >> 3, j = t & 7;
  __shared__ float us[2][D_], hs[2][D_], xs2[2][D_];
  __shared__ float gi_l[2][768], gh_l[2][768];
  __shared__ float h2s[2][HID_];
  __shared__ float o2[2][D_];
  __shared__ float red[4 * 2 * 2];
  const long base = (long)(b * S_ + i0) * D_;
#pragma unroll
  for (int ii = 0; ii < 2; ++ii){
    int si = b*S_ + i0 + ii;
    float dv = denP[si] + denP[512 + si];
    long ni = (long)si * D_ + t;
    us[ii][t] = (numP[ni] + numP[131072 + ni]) / dv;
    hs[ii][t] = slots_in[base + ii*D_ + t];
  }
  __syncthreads();
  for (int q = 0; q < 24; ++q){
    const int gcol = grp + q * 32;
    const float4* wi = (const float4*)(w_ih + (long)gcol * D_) + j;
    const float4* wh = (const float4*)(w_hh + (long)gcol * D_) + j;
    float ai[2] = {0,0}, ah[2] = {0,0};
#pragma unroll
    for (int c = 0; c < 8; ++c){
      float4 wf = wi[c*8];
      float4 hf = wh[c*8];
      const int k4 = (j + c*8) * 4;
#pragma unroll
      for (int ii = 0; ii < 2; ++ii){
        float4 uf = *(const float4*)(&us[ii][k4]);
        float4 hv = *(const float4*)(&hs[ii][k4]);
        ai[ii] += wf.x*uf.x + wf.y*uf.y + wf.z*uf.z + wf.w*uf.w;
        ah[ii] += hf.x*hv.x + hf.y*hv.y + hf.z*hv.z + hf.w*hv.w;
      }
    }
#pragma unroll
    for (int o = 1; o < 8; o <<= 1){
#pragma unroll
      for (int ii = 0; ii < 2; ++ii){ ai[ii] += __shfl_xor(ai[ii], o); ah[ii] += __shfl_xor(ah[ii], o); }
    }
    if (j == 0){
#pragma unroll
      for (int ii = 0; ii < 2; ++ii){ gi_l[ii][gcol] = ai[ii]; gh_l[ii][gcol] = ah[ii]; }
    }
  }
  __syncthreads();
  const float bir = b_ih[t], biz = b_ih[256 + t], bin_ = b_ih[512 + t];
  const float bhr = b_hh[t], bhz = b_hh[256 + t], bhn = b_hh[512 + t];
  float nh[2];
#pragma unroll
  for (int ii = 0; ii < 2; ++ii){
    float r = 1.f / (1.f + __expf(-(gi_l[ii][t] + bir + gh_l[ii][t] + bhr)));
    float z = 1.f / (1.f + __expf(-(gi_l[ii][256 + t] + biz + gh_l[ii][256 + t] + bhz)));
    float n = tanhf(gi_l[ii][512 + t] + bin_ + r * (gh_l[ii][512 + t] + bhn));
    nh[ii] = (1.f - z) * n + z * hs[ii][t];
  }
  float mean[2], rstd[2];
  stats2(nh, red, t, mean, rstd);
  const float fgv = fg[t], fbv = fb[t];
#pragma unroll
  for (int ii = 0; ii < 2; ++ii) xs2[ii][t] = (nh[ii] - mean[ii]) * rstd[ii] * fgv + fbv;
  __syncthreads();
  for (int q = 0; q < 16; ++q){
    const int gcol = grp + q * 32;
    const float4* wr = (const float4*)(w1 + (long)gcol * D_) + j;
    float a[2] = {0,0};
#pragma unroll
    for (int c = 0; c < 8; ++c){
      float4 wf = wr[c*8];
      const int k4 = (j + c*8) * 4;
#pragma unroll
      for (int ii = 0; ii < 2; ++ii){
        float4 xf = *(const float4*)(&xs2[ii][k4]);
        a[ii] += wf.x*xf.x + wf.y*xf.y + wf.z*xf.z + wf.w*xf.w;
      }
    }
#pragma unroll
    for (int o = 1; o < 8; o <<= 1)
#pragma unroll
      for (int ii = 0; ii < 2; ++ii) a[ii] += __shfl_xor(a[ii], o);
    if (j == 0){
      float bb = b1[gcol];
#pragma unroll
      for (int ii = 0; ii < 2; ++ii) h2s[ii][gcol] = fmaxf(a[ii] + bb, 0.f);
    }
  }
  __syncthreads();
  for (int q = 0; q < 8; ++q){
    const int gcol = grp + q * 32;
    const float4* wr = (const float4*)(w2 + (long)gcol * HID_) + j;
    float a[2] = {0,0};
#pragma unroll
    for (int c = 0; c < 16; ++c){
      float4 wf = wr[c*8];
      const int k4 = (j + c*8) * 4;
#pragma unroll
      for (int ii = 0; ii < 2; ++ii){
        float4 xf = *(const float4*)(&h2s[ii][k4]);
        a[ii] += wf.x*xf.x + wf.y*xf.y + wf.z*xf.z + wf.w*xf.w;
      }
    }
#pragma unroll
    for (int o = 1; o < 8; o <<= 1)
#pragma unroll
      for (int ii = 0; ii < 2; ++ii) a[ii] += __shfl_xor(a[ii], o);
    if (j == 0){
#pragma unroll
      for (int ii = 0; ii < 2; ++ii) o2[ii][gcol] = a[ii];
    }
  }
  __syncthreads();
  float outv[2];
  const float b2v = b2[t];
#pragma unroll
  for (int ii = 0; ii < 2; ++ii){
    outv[ii] = nh[ii] + o2[ii][t] + b2v;
    outp[base + ii*D_ + t] = outv[ii];
  }
  if (write_q){
    float mean2[2], rstd2[2];
    stats2(outv, red, t, mean2, rstd2);
    const float lg2 = lsg[t], lb2 = lsb[t];
#pragma unroll
    for (int ii = 0; ii < 2; ++ii) xs2[ii][t] = (outv[ii] - mean2[ii]) * rstd2[ii] * lg2 + lb2;
    __syncthreads();
    for (int q = 0; q < 8; ++q){
      const int gcol = grp + q * 32;
      const float4* wr = (const float4*)(wq + (long)gcol * D_) + j;
      float a[2] = {0,0};
#pragma unroll
      for (int c = 0; c < 8; ++c){
        float4 wf = wr[c*8];
        const int k4 = (j + c*8) * 4;
#pragma unroll
        for (int ii = 0; ii < 2; ++ii){
          float4 xf = *(const float4*)(&xs2[ii][k4]);
          a[ii] += wf.x*xf.x + wf.y*xf.y + wf.z*xf.z + wf.w*xf.w;
        }
      }
#pragma unroll
      for (int o = 1; o < 8; o <<= 1)
#pragma unroll
        for (int ii = 0; ii < 2; ++ii) a[ii] += __shfl_xor(a[ii], o);
      if (j == 0){
        float bb = bq[gcol];
#pragma unroll
        for (int ii = 0; ii < 2; ++ii) qout[(long)(b*S_ + i0 + ii)*D_ + gcol] = a[ii] + bb;
      }
    }
  }
}

// ---------------- host ------------------------------------------------------
extern "C" void kernel_launch(void* const* d_in, const int* in_sizes, int n_in,
                              void* d_out, int out_size, void* d_ws, size_t ws_size,
                              hipStream_t stream)
{
  const float* inputs     = (const float*)d_in[0];
  const float* slots_init = (const float*)d_in[1];
  const float* slots_mu   = (const float*)d_in[2];
  const float* slots_sig  = (const float*)d_in[3];
  const float* wq   = (const float*)d_in[4];
  const float* bq   = (const float*)d_in[5];
  const float* wk   = (const float*)d_in[6];
  const float* bk   = (const float*)d_in[7];
  const float* wv   = (const float*)d_in[8];
  const float* bv   = (const float*)d_in[9];
  const float* w_ih = (const float*)d_in[10];
  const float* b_ih = (const float*)d_in[11];
  const float* w_hh = (const float*)d_in[12];
  const float* b_hh = (const float*)d_in[13];
  const float* w1   = (const float*)d_in[14];
  const float* b1   = (const float*)d_in[15];
  const float* w2   = (const float*)d_in[16];
  const float* b2   = (const float*)d_in[17];
  const float* lig  = (const float*)d_in[18];
  const float* lib  = (const float*)d_in[19];
  const float* lsg  = (const float*)d_in[20];
  const float* lsb  = (const float*)d_in[21];
  const float* ffg  = (const float*)d_in[22];
  const float* ffb  = (const float*)d_in[23];
  float* out = (float*)d_out;

  // ws layout (270,016,512 B <= proven):
  //   qbuf  @ 0         (524,288)
  //   numP  @ 524,288   (1,048,576 = 2 copies) -- wkv aliases its first 256 KB
  //   denP  @ 1,572,864 (4,096 = 2 copies)
  //   kv    @ 1,576,960 (268,435,456) -- x_hat aliases kv[r][0..255] pre-kG
  // slots lives in d_out (in-place across iterations).
  char* ws = (char*)d_ws;
  float* qbuf = (float*)(ws);
  float* numP = (float*)(ws + 524288);
  unsigned short* wkv = (unsigned short*)(ws + 524288);
  float* denP = (float*)(ws + 1572864);
  unsigned short* kv = (unsigned short*)(ws + 1576960);
  float* slots = out;

  kW<<<512, 256, 0, stream>>>(wk, wv, wkv);
  kLN<<<2048, 256, 0, stream>>>(inputs, lig, lib, kv);
  kG<<<4096, 512, 0, stream>>>(wkv, bk, bv, kv);
  kI<<<64, 256, 0, stream>>>(slots_init, slots_mu, slots_sig, lsg, lsb, wq, bq, slots, qbuf);
  for (int it = 0; it < 3; ++it){
    hipMemsetAsync(numP, 0, 1048576 + 4096, stream);
    kD<<<dim3(16, 64), 256, 0, stream>>>(kv, qbuf, numP, denP);
    kS<<<256, 256, 0, stream>>>(numP, denP, slots, w_ih, b_ih, w_hh, b_hh,
                                w1, b1, w2, b2, ffg, ffb, lsg, lsb, wq, bq,
                                slots, qbuf, (it < 2) ? 1 : 0);
  }
}